// Round 3
// baseline (195.727 us; speedup 1.0000x reference)
//
#include <hip/hip_runtime.h>
#include <hip/hip_bf16.h>
#include <math.h>
#include <stdint.h>

// Problem constants (reference: B=4, T=2048, C=1024, H=16, HD=64)
#define BB 4
#define TT 2048
#define CC 1024
#define HH 16
#define HD 64
#define MM (BB*TT)   // 8192
#define NQT 8        // T / 256 q-tiles for attention (QBLK=256)
#define SCQ 0.180336878f   // (1/sqrt(HD)) * log2(e): Q pre-scale for exp2-domain softmax

using f32x4  = __attribute__((ext_vector_type(4))) float;
using f32x16 = __attribute__((ext_vector_type(16))) float;
using i32x4  = __attribute__((ext_vector_type(4))) int;
using bf16x4 = __attribute__((ext_vector_type(4))) __bf16;
using bf16x8 = __attribute__((ext_vector_type(8))) __bf16;

__device__ __forceinline__ float fast_exp2(float x) {
  return __builtin_amdgcn_exp2f(x);   // v_exp_f32 (native exp2 on gfx950)
}

__device__ __forceinline__ int cvt_pk_bf16(float lo, float hi_) {
  int r;
  asm("v_cvt_pk_bf16_f32 %0, %1, %2" : "=v"(r) : "v"(lo), "v"(hi_));
  return r;   // low 16 = bf16(lo), high 16 = bf16(hi_)
}

__device__ __forceinline__ void gload_lds16(const void* g, void* l) {
  __builtin_amdgcn_global_load_lds(
      (__attribute__((address_space(1))) void*)(void*)(g),
      (__attribute__((address_space(3))) void*)(l), 16, 0, 0);
}

// ---------------- fp32 -> bf16 converts ----------------
__global__ __launch_bounds__(256)
void cvt_f32_bf16(const float* __restrict__ s, __bf16* __restrict__ d, int n4) {
  int i = blockIdx.x * 256 + threadIdx.x;
  if (i >= n4) return;
  float4 v = ((const float4*)s)[i];
  bf16x4 o;
  o[0] = (__bf16)v.x; o[1] = (__bf16)v.y; o[2] = (__bf16)v.z; o[3] = (__bf16)v.w;
  *(bf16x4*)(d + (size_t)i * 4) = o;
}

// 4 weights in one launch; Wq scaled by SCQ and Wq/Wk/Wv written into the
// contiguous [3072][1024] concat buffer (order q,k,v); Wp separate.
__global__ __launch_bounds__(256)
void cvt_w4(const float* __restrict__ Wq, const float* __restrict__ Wk,
            const float* __restrict__ Wv, const float* __restrict__ Wp,
            __bf16* __restrict__ wqkv, __bf16* __restrict__ wpb) {
  int which = blockIdx.y;
  const float* s = which == 0 ? Wq : which == 1 ? Wk : which == 2 ? Wv : Wp;
  __bf16* d = which == 3 ? wpb : wqkv + (size_t)which * CC * CC;
  float sc = which == 0 ? SCQ : 1.f;
  int i = blockIdx.x * 256 + threadIdx.x;   // grid.x = (CC*CC/4)/256 = 1024
  float4 v = ((const float4*)s)[i];
  bf16x4 o;
  o[0] = (__bf16)(v.x * sc); o[1] = (__bf16)(v.y * sc);
  o[2] = (__bf16)(v.z * sc); o[3] = (__bf16)(v.w * sc);
  *(bf16x4*)(d + (size_t)i * 4) = o;
}

// ================== 8-phase 256x256 BK=64 QKV GEMM (m201 schedule) ==========
// C[8192,3072] = A[8192,1024] x Wqkv[3072,1024]^T + bias.
// proj 0/1 (Q,K): bf16 head-split [proj][B,H,T,HD] store.
// proj 2 (V): epilogue transposes the 256x256 tile through LDS (4 chunks of
// 64 cols) and writes Vt[bh][d][t] coalesced — replaces the transpose kernel.
#define WAITV6 asm volatile("s_waitcnt vmcnt(6)" ::: "memory")
#define WAITV4 asm volatile("s_waitcnt vmcnt(4)" ::: "memory")
#define WAITV2 asm volatile("s_waitcnt vmcnt(2)" ::: "memory")
#define WAITV0 asm volatile("s_waitcnt vmcnt(0)" ::: "memory")
#define WAITL0 asm volatile("s_waitcnt lgkmcnt(0)" ::: "memory")
#define BARR   __builtin_amdgcn_s_barrier()
#define SB0    __builtin_amdgcn_sched_barrier(0)
#define PRIO1  __builtin_amdgcn_s_setprio(1)
#define PRIO0  __builtin_amdgcn_s_setprio(0)

#define LDA_SET(buf, mq)                                                      \
  {                                                                           \
    const char* base_ = (const char*)&LA[buf][mq][0] + (wm * 64 + lq) * 128;  \
    _Pragma("unroll")                                                         \
    for (int m4 = 0; m4 < 4; ++m4)                                            \
      _Pragma("unroll")                                                       \
      for (int kk = 0; kk < 2; ++kk)                                          \
        a[m4 * 2 + kk] =                                                      \
            *(const bf16x8*)(base_ + m4 * 2048 + ((kk * 64 + g * 16) ^ swz)); \
  }

#define LDB_SET(buf, nq)                                                      \
  {                                                                           \
    const char* base_ = (const char*)&LB[buf][nq][0] + (wn * 32 + lq) * 128;  \
    _Pragma("unroll")                                                         \
    for (int n2 = 0; n2 < 2; ++n2)                                            \
      _Pragma("unroll")                                                       \
      for (int kk = 0; kk < 2; ++kk)                                          \
        b[nq][n2 * 2 + kk] =                                                  \
            *(const bf16x8*)(base_ + n2 * 2048 + ((kk * 64 + g * 16) ^ swz)); \
  }

#define STAGE_A(nbuf, h, tt)                                                  \
  {                                                                           \
    const char* s_ = Ag + ((size_t)((h)*128 + srow)) * 2048 + (tt)*128 + scol1; \
    gload_lds16(s_, (char*)&LA[nbuf][h][0] + so16);                           \
    gload_lds16(s_ + (size_t)64 * 2048, (char*)&LA[nbuf][h][0] + so16 + 8192);\
  }

#define STAGE_B(nbuf, h, tt)                                                  \
  {                                                                           \
    const char* s_ = Bg + ((size_t)((h)*128 + srow)) * 2048 + (tt)*128 + scol1; \
    gload_lds16(s_, (char*)&LB[nbuf][h][0] + so16);                           \
    gload_lds16(s_ + (size_t)64 * 2048, (char*)&LB[nbuf][h][0] + so16 + 8192);\
  }

#define MFMA_PH(mq, nq)                                                       \
  _Pragma("unroll")                                                           \
  for (int m4 = 0; m4 < 4; ++m4)                                              \
    _Pragma("unroll")                                                         \
    for (int n2 = 0; n2 < 2; ++n2)                                            \
      _Pragma("unroll")                                                       \
      for (int kk = 0; kk < 2; ++kk)                                          \
        acc[mq][m4][nq][n2] = __builtin_amdgcn_mfma_f32_16x16x32_bf16(        \
            a[m4 * 2 + kk], b[nq][n2 * 2 + kk], acc[mq][m4][nq][n2], 0, 0, 0);

__global__ __launch_bounds__(512, 2)
void gemm_qkv(const __bf16* __restrict__ A, const __bf16* __restrict__ Bm,
              const float* __restrict__ b0, const float* __restrict__ b1,
              const float* __restrict__ b2, __bf16* __restrict__ out,
              __bf16* __restrict__ vt) {
  __shared__ __bf16 LA[2][2][128 * 64];   // [K-tile parity][half][128 x 64]
  __shared__ __bf16 LB[2][2][128 * 64];   // 128 KiB total
  const int tid = threadIdx.x, wid = tid >> 6, lane = tid & 63;
  const int g = lane >> 4, lq = lane & 15;
  const int wm = wid >> 2, wn = wid & 3;             // 2M x 4N waves
  const int bm = blockIdx.x / 12, bn = blockIdx.x % 12;
  const int brow = bm << 8, bcol = bn << 8;
  const int swz = (lq & 7) << 4;

  // staging geometry: thread stages 2x16B chunks per half-tile
  const int srow = tid >> 3, so16 = tid * 16;
  const int scol1 = ((tid & 7) << 4) ^ ((srow & 7) << 4);  // inverse-swizzled src col
  const char* Ag = (const char*)A + (size_t)brow * 2048;   // K=1024 -> 2048B rows
  const char* Bg = (const char*)Bm + (size_t)bcol * 2048;

  f32x4 acc[2][4][2][2] = {};
  bf16x8 a[8], b[2][4];

  // prologue: 7 halves = tile0 {A0,B0,B1,A1} + tile1 {A0,B0,B1}
  STAGE_A(0, 0, 0); STAGE_B(0, 0, 0); STAGE_B(0, 1, 0); STAGE_A(0, 1, 0);
  STAGE_A(1, 0, 1); STAGE_B(1, 0, 1); STAGE_B(1, 1, 1);
  WAITV6; BARR;

#pragma unroll 1
  for (int t = 0; t < 8; ++t) {
    const bool s2 = (t < 7);
    const int k1 = 2 * t + 1, k2 = 2 * t + 2, k3 = 2 * t + 3;
    // ---- p1: tile 2t (buf0) quad (0,0); stage A1(2t+1) ----
    LDA_SET(0, 0); LDB_SET(0, 0);
    STAGE_A(1, 1, k1);
    BARR; WAITL0; SB0;
    PRIO1; MFMA_PH(0, 0); PRIO0; BARR;
    // ---- p2: quad (0,1); stage A0(2t+2) ----
    LDB_SET(0, 1);
    if (s2) STAGE_A(0, 0, k2);
    BARR; WAITL0; SB0;
    PRIO1; MFMA_PH(0, 1); PRIO0; BARR;
    // ---- p3: quad (1,1); stage B0(2t+2) ----
    LDA_SET(0, 1);
    if (s2) STAGE_B(0, 0, k2);
    BARR; WAITL0; SB0;
    PRIO1; MFMA_PH(1, 1); PRIO0; BARR;
    // ---- p4: quad (1,0); stage B1(2t+2); counted vmcnt ----
    if (s2) { STAGE_B(0, 1, k2); WAITV6; } else { WAITV0; }
    BARR; SB0;
    PRIO1; MFMA_PH(1, 0); PRIO0; BARR;
    // ---- p5: tile 2t+1 (buf1) quad (0,0); stage A1(2t+2) ----
    LDA_SET(1, 0); LDB_SET(1, 0);
    if (s2) STAGE_A(0, 1, k2);
    BARR; WAITL0; SB0;
    PRIO1; MFMA_PH(0, 0); PRIO0; BARR;
    // ---- p6: quad (0,1); stage A0(2t+3) ----
    LDB_SET(1, 1);
    if (s2) STAGE_A(1, 0, k3);
    BARR; WAITL0; SB0;
    PRIO1; MFMA_PH(0, 1); PRIO0; BARR;
    // ---- p7: quad (1,1); stage B0(2t+3) ----
    LDA_SET(1, 1);
    if (s2) STAGE_B(1, 0, k3);
    BARR; WAITL0; SB0;
    PRIO1; MFMA_PH(1, 1); PRIO0; BARR;
    // ---- p8: quad (1,0); stage B1(2t+3); counted vmcnt ----
    if (s2) { STAGE_B(1, 1, k3); WAITV6; }
    BARR; SB0;
    PRIO1; MFMA_PH(1, 0); PRIO0; BARR;
  }

  const int proj = bn >> 2;   // uniform per block (256 | 1024)
  if (proj < 2) {
    // epilogue: bias + bf16 head-split store [proj][B,H,T,HD]
    const float* bias = proj == 0 ? b0 : b1;
    const float bsc = proj == 0 ? SCQ : 1.f;
#pragma unroll
    for (int mq = 0; mq < 2; ++mq)
#pragma unroll
      for (int nq = 0; nq < 2; ++nq)
#pragma unroll
        for (int n2 = 0; n2 < 2; ++n2) {
          int col = bcol + nq * 128 + wn * 32 + n2 * 16 + lq;
          int cw = col & (CC - 1);
          float bb = bias[cw] * bsc;
          int h_ = cw >> 6, d_ = cw & (HD - 1);
#pragma unroll
          for (int m4 = 0; m4 < 4; ++m4) {
            int row0 = brow + mq * 128 + wm * 64 + m4 * 16 + g * 4;
#pragma unroll
            for (int i = 0; i < 4; ++i) {
              int row = row0 + i;
              int b_ = row >> 11, t_ = row & (TT - 1);
              out[((size_t)proj << 23) +
                  ((((size_t)b_ * HH + h_) * TT + t_) << 6) + d_] =
                  (__bf16)(acc[mq][m4][nq][n2][i] + bb);
            }
          }
        }
  } else {
    // V: transpose 256x256 tile through LDS (4 chunks of 64 cols = 1 head
    // each) and write Vt[bh][d][t] coalesced. LDS main buffers are free.
    __bf16* lt = (__bf16*)&LA[0][0][0];          // [64 cols][264 rows]
    const int cv0 = (bn & 3) << 8;               // col offset within V region
    const int b_ = brow >> 11, t0 = brow & (TT - 1);
    const int hbase = (bn & 3) << 2;
    const int rd_d = tid >> 3, rd_tb = (tid & 7) << 5;
#pragma unroll
    for (int cc = 0; cc < 4; ++cc) {
      if ((wn >> 1) == (cc & 1)) {               // 4 writer waves per chunk
#pragma unroll
        for (int n2 = 0; n2 < 2; ++n2) {
          int c = ((wn & 1) << 5) + (n2 << 4) + lq;
          float bb = b2[cv0 + (cc << 6) + c];
#pragma unroll
          for (int mq = 0; mq < 2; ++mq)
#pragma unroll
            for (int m4 = 0; m4 < 4; ++m4) {
              int r = (mq << 7) + (wm << 6) + (m4 << 4) + (g << 2);
              bf16x4 pk;
#pragma unroll
              for (int i = 0; i < 4; ++i)
                pk[i] = (__bf16)(acc[mq][m4][cc >> 1][n2][i] + bb);
              *(bf16x4*)(lt + c * 264 + r) = pk;
            }
        }
      }
      __syncthreads();
      // readers: all 512 threads; d = tid>>3, 32 t-elems each
      __bf16* dst = vt + (((size_t)((b_ * HH + hbase + cc) * HD + rd_d)) << 11)
                       + t0 + rd_tb;
      const __bf16* srcl = lt + rd_d * 264 + rd_tb;
#pragma unroll
      for (int j = 0; j < 4; ++j)
        *(bf16x8*)(dst + j * 8) = *(const bf16x8*)(srcl + j * 8);
      __syncthreads();
    }
  }
}

// ---------------- proj GEMM (m97 structure): fp32 out ----------------
__global__ __launch_bounds__(256, 2)
void gemm_proj(const __bf16* __restrict__ A, const __bf16* __restrict__ Bm,
               const float* __restrict__ bias, float* __restrict__ out,
               int M, int N, int K) {
  __shared__ __bf16 As[128 * 32];
  __shared__ __bf16 Bs[128 * 32];
  const int tid = threadIdx.x;
  const int wid = tid >> 6, lane = tid & 63;
  const int g = lane >> 4, lq = lane & 15;
  const int nbn = N >> 7;
  const int brow = (blockIdx.x / nbn) << 7;
  const int bcol = (blockIdx.x % nbn) << 7;
  const int wr = (wid >> 1) << 6, wc = (wid & 1) << 6;

  f32x4 acc[4][4] = {};

  const int o0 = wid * 2048 + lane * 16;
  for (int kt = 0; kt < K; kt += 32) {
    __syncthreads();
#pragma unroll
    for (int j = 0; j < 2; ++j) {
      int o = o0 + j * 1024;
      int row = o >> 6, colb = o & 63;
      gload_lds16((const char*)A + ((size_t)(brow + row) * K + kt) * 2 + colb,
                  (char*)As + o);
      gload_lds16((const char*)Bm + ((size_t)(bcol + row) * K + kt) * 2 + colb,
                  (char*)Bs + o);
    }
    __syncthreads();
    bf16x8 av[4], bv[4];
#pragma unroll
    for (int m = 0; m < 4; ++m)
      av[m] = *(const bf16x8*)(As + (wr + m * 16 + lq) * 32 + g * 8);
#pragma unroll
    for (int n = 0; n < 4; ++n)
      bv[n] = *(const bf16x8*)(Bs + (wc + n * 16 + lq) * 32 + g * 8);
#pragma unroll
    for (int m = 0; m < 4; ++m)
#pragma unroll
      for (int n = 0; n < 4; ++n)
        acc[m][n] = __builtin_amdgcn_mfma_f32_16x16x32_bf16(av[m], bv[n], acc[m][n], 0, 0, 0);
  }

#pragma unroll
  for (int m = 0; m < 4; ++m) {
#pragma unroll
    for (int n = 0; n < 4; ++n) {
      int col = bcol + wc + n * 16 + lq;
      float bb = bias[col];
      int row0 = brow + wr + m * 16 + g * 4;
#pragma unroll
      for (int i = 0; i < 4; ++i)
        out[(size_t)(row0 + i) * N + col] = acc[m][n][i] + bb;
    }
  }
}

// ---------------- Flash attention v4 (causal + padding mask) ----------------
// grid 512 = 8 q-tiles x 64 bh, 512 threads = 8 waves x 32 q-rows (QBLK=256).
// 32x32x16 MFMA, swapped QK^T, split-half S (one f32x16 live).
// NEW vs v3:
//  * padding-mask hoisted to ONE block-level check (LDS flag) -> fast path has
//    ZERO global loads / ballots in the K/V loop (no per-tile vmem waits).
//  * TRIPLE-buffered K/V staging with counted vmcnt (never drains to 0 in
//    steady state): stage(t+3) issued after compute(t); wait for stage(t+1)
//    gets ~2 full compute phases of latency-hiding. Raw s_barrier pairs with
//    sched_barrier(0) fences (no __syncthreads vmcnt(0) drain per tile).
//  * launch_bounds(512,3): VGPR cap ~168 (anti-spill insurance; live ~100).
// C/D layout (m74/m101): col = lane&31, row = (r&3) + 8*(r>>2) + 4*(lane>>5).
__global__ __launch_bounds__(512, 3)
void attn_fwd(const __bf16* __restrict__ Q, const __bf16* __restrict__ K,
              const __bf16* __restrict__ Vt, const int* __restrict__ pm,
              __bf16* __restrict__ Y) {
  __shared__ __bf16 Ks[3][64 * 64];
  __shared__ __bf16 Vs[3][64 * 64];
  __shared__ int flg;
  const int tid = threadIdx.x, wid = tid >> 6, lane = tid & 63;
  const int l31 = lane & 31, hi = lane >> 5;
  const int bx = blockIdx.x;
  const int bh = bx & 63, jj = bx >> 6;
  // qi order: balanced for both consecutive-pair and +256-pair block->CU
  // mappings: {7,5,6,4,0,2,1,3}
  const int r2 = ((jj & 1) << 1) | ((jj >> 1) & 1);
  const int qi = (jj & 4) ? r2 : 7 - r2;
  const int b_ = bh >> 4, h_ = bh & 15;
  const __bf16* Qb = Q + (size_t)bh * TT * HD;
  const __bf16* Kb = K + (size_t)bh * TT * HD;
  const __bf16* Vb = Vt + (size_t)bh * HD * TT;
  const int* pmb = pm + b_ * TT;

  const int so = tid * 16;                 // this thread's 16B staging chunk
  const int srow = so >> 7, scol = (so & 127) ^ ((srow & 7) << 4);

  const int q0 = qi << 8;
  const int qw = q0 + wid * 32;            // this wave's 32 q-rows
  const int ntiles = 4 * qi + 4;           // >= 4 always
  const int sw0 = (l31 & 7) << 4;

  // Q fragments FIRST (so their vmem wait precedes staging issues):
  // lane holds Q[qw+l31][16s + 8hi .. +7], s=0..3
  bf16x8 qf[4];
#pragma unroll
  for (int s = 0; s < 4; ++s)
    qf[s] = *(const bf16x8*)(Qb + (size_t)(qw + l31) * HD + s * 16 + hi * 8);

  // padding-mask block check: 512 threads x int4 covers the 2048-int pm row
  int4 pm4 = ((const int4*)pmb)[tid];
  bool okp = pm4.x && pm4.y && pm4.z && pm4.w;
  if (tid == 0) flg = 1;

  // staging pointers (tile n: K src += n*8192B, V src += n*128B, dst buf n%3)
  const char* ksrc = (const char*)Kb + (size_t)srow * 128 + scol;
  const char* vsrc = (const char*)Vb + (size_t)srow * (TT * 2) + scol;
  char* kdst = (char*)&Ks[0][0] + so;
  char* vdst = (char*)&Vs[0][0] + so;

  // prologue: stage tiles 0,1,2
#pragma unroll
  for (int n = 0; n < 3; ++n) {
    gload_lds16(ksrc + (size_t)n * 8192, kdst + n * 8192);
    gload_lds16(vsrc + (size_t)n * 128, vdst + n * 8192);
  }
  WAITL0; BARR; SB0;          // flg=1 visible to all
  if (!okp) flg = 0;          // benign race (all writers store 0)
  WAITL0; WAITV4; BARR; SB0;  // tile0 staged everywhere; flg final
  const bool allones = (flg != 0);

  f32x16 o0 = {}, o1 = {};                 // O[q=crow(r,hi)][d = l31 | 32+l31]
  float lsum = 0.f;                        // partial row-sum (this lane-half)
  float m = -INFINITY;                     // running max for q = qw+l31

  int cur = 0;
#pragma unroll 1
  for (int t = 0; t < ntiles; ++t) {
    const int kv0 = t << 6;
    unsigned long long bits = ~0ull;
    if (__builtin_expect(!allones, 0)) {   // rare slow path
      int pmv = pmb[kv0 + lane];
      bits = __ballot(pmv != 0);
    }

    if (kv0 <= qw + 31) {                  // wave-uniform participation
      const char* VsC = (const char*)&Vs[0][0] + cur * 8192;

#pragma unroll
      for (int h = 0; h < 2; ++h) {
        const int kvh = kv0 + 32 * h;
        if (kvh <= qw + 31) {              // wave-uniform per-half gate
          // ---- QK^T (swapped): S[kvh+crow][q=l31] ----
          const char* KsC =
              (const char*)&Ks[0][0] + cur * 8192 + (32 * h + l31) * 128;
          f32x16 S = {};
          __builtin_amdgcn_s_setprio(1);
#pragma unroll
          for (int s = 0; s < 4; ++s) {
            bf16x8 kf = *(const bf16x8*)(KsC + ((32 * s + 16 * hi) ^ sw0));
            S = __builtin_amdgcn_mfma_f32_32x32x16_bf16(kf, qf[s], S, 0, 0, 0);
          }
          __builtin_amdgcn_s_setprio(0);

          // ---- masks ----
          if (__builtin_expect(bits != ~0ull, 0)) {   // padding (rare)
#pragma unroll
            for (int r = 0; r < 16; ++r) {
              const int c = (r & 3) + 8 * (r >> 2);
              if (!((bits >> (32 * h + c + 4 * hi)) & 1ull)) S[r] = -INFINITY;
            }
          }
          if (kvh + 31 > qw) {             // causal diag (wave-uniform)
            const int thr = qw + l31 - kvh - 4 * hi;
#pragma unroll
            for (int r = 0; r < 16; ++r) {
              const int c = (r & 3) + 8 * (r >> 2);
              S[r] = (c <= thr) ? S[r] : -INFINITY;
            }
          }

          // ---- partial row max (tree) + defer-rescale check ----
          float t0 = fmaxf(fmaxf(S[0], S[1]), fmaxf(S[2], S[3]));
          float t1 = fmaxf(fmaxf(S[4], S[5]), fmaxf(S[6], S[7]));
          float t2 = fmaxf(fmaxf(S[8], S[9]), fmaxf(S[10], S[11]));
          float t3 = fmaxf(fmaxf(S[12], S[13]), fmaxf(S[14], S[15]));
          float pmax = fmaxf(fmaxf(t0, t1), fmaxf(t2, t3));
          if (!__all(pmax <= m + 8.f)) {
            float nm = fmaxf(pmax, __shfl_xor(pmax, 32));  // full row max
            float mn = fmaxf(m, nm);
            float c = fast_exp2(m - mn);
            m = mn;
            lsum *= c;
#pragma unroll
            for (int r = 0; r < 16; ++r) {
              float cr = __shfl(c, (r & 3) + 8 * (r >> 2) + 4 * hi);
              o0[r] *= cr;
              o1[r] *= cr;
            }
          }

          // ---- P = exp2(S - m); in-lane row-sum ----
#pragma unroll
          for (int r = 0; r < 16; ++r) S[r] = fast_exp2(S[r] - m);
          {
            float u0 = (S[0] + S[1]) + (S[2] + S[3]);
            float u1 = (S[4] + S[5]) + (S[6] + S[7]);
            float u2 = (S[8] + S[9]) + (S[10] + S[11]);
            float u3 = (S[12] + S[13]) + (S[14] + S[15]);
            lsum += (u0 + u1) + (u2 + u3);
          }

          // ---- PV: build A-fragments in-register, accumulate O ----
          __builtin_amdgcn_s_setprio(1);
#pragma unroll
          for (int s = 0; s < 2; ++s) {
            const int ub = 2 * s;
            int A0 = cvt_pk_bf16(S[4 * ub + 0], S[4 * ub + 1]);
            int A1 = cvt_pk_bf16(S[4 * ub + 2], S[4 * ub + 3]);
            int B0 = cvt_pk_bf16(S[4 * ub + 4], S[4 * ub + 5]);
            int B1 = cvt_pk_bf16(S[4 * ub + 6], S[4 * ub + 7]);
            // exchange across lane+-32: hi=0 needs partner's A-pair, hi=1 B-pair
            int s0 = hi ? A0 : B0, s1 = hi ? A1 : B1;
            int e0 = __shfl_xor(s0, 32), e1 = __shfl_xor(s1, 32);
            i32x4 wv;
            wv[0] = hi ? e0 : A0;
            wv[1] = hi ? e1 : A1;
            wv[2] = hi ? B0 : e0;
            wv[3] = hi ? B1 : e1;
            bf16x8 pa = __builtin_bit_cast(bf16x8, wv);
            const int co = 64 * h + 32 * s + 16 * hi;   // kv byte offset
            bf16x8 v0 = *(const bf16x8*)(VsC + l31 * 128 + (co ^ sw0));
            bf16x8 v1 = *(const bf16x8*)(VsC + (32 + l31) * 128 + (co ^ sw0));
            o0 = __builtin_amdgcn_mfma_f32_32x32x16_bf16(pa, v0, o0, 0, 0, 0);
            o1 = __builtin_amdgcn_mfma_f32_32x32x16_bf16(pa, v1, o1, 0, 0, 0);
          }
          __builtin_amdgcn_s_setprio(0);
          __builtin_amdgcn_sched_barrier(0);  // keep halves' S non-overlapping
        }
      }
    }

    // ---- pipeline maintenance (counted vmcnt, raw barriers) ----
    BARR; SB0;                             // all reads of buf[cur] done
    if (t + 3 < ntiles) {                  // stage tile t+3 into buf[cur]
      gload_lds16(ksrc + (size_t)(t + 3) * 8192, kdst + cur * 8192);
      gload_lds16(vsrc + (size_t)(t + 3) * 128, vdst + cur * 8192);
      WAITV4;                              // stage(t+1) done; t+2,t+3 in flight
    } else if (t + 2 < ntiles) {
      WAITV2;                              // stage(t+1) done; t+2 in flight
    } else if (t + 1 < ntiles) {
      WAITV0;                              // last staged tile done
    }
    BARR; SB0;                             // publish tile t+1 to all waves
    cur = (cur == 2) ? 0 : cur + 1;
  }

  // epilogue: combine lane-halves' row-sums, normalize + store
  float linv = 1.f / (lsum + __shfl_xor(lsum, 32));
#pragma unroll
  for (int r = 0; r < 16; ++r) {
    const int crow = (r & 3) + 8 * (r >> 2) + 4 * hi;
    float ir = __shfl(linv, crow);
    const int qrow = qw + crow;
    __bf16* yp = Y + ((size_t)(b_ * TT + qrow)) * CC + h_ * HD + l31;
    yp[0]  = (__bf16)(o0[r] * ir);
    yp[32] = (__bf16)(o1[r] * ir);
  }
}

// ---------------- launch ----------------
extern "C" void kernel_launch(void* const* d_in, const int* in_sizes, int n_in,
                              void* d_out, int out_size, void* d_ws, size_t ws_size,
                              hipStream_t stream) {
  (void)in_sizes; (void)n_in; (void)out_size; (void)ws_size;
  const float* x  = (const float*)d_in[0];
  const float* Wk = (const float*)d_in[1];
  const float* bk = (const float*)d_in[2];
  const float* Wq = (const float*)d_in[3];
  const float* bq = (const float*)d_in[4];
  const float* Wv = (const float*)d_in[5];
  const float* bv = (const float*)d_in[6];
  const float* Wp = (const float*)d_in[7];
  const float* bp = (const float*)d_in[8];
  const int* pmask = (const int*)d_in[9];

  char* ws = (char*)d_ws;
  const size_t MB = 1024 * 1024;
  __bf16* xb   = (__bf16*)(ws);            // 16MB; reused as attn-out y
  __bf16* wqkv = (__bf16*)(ws + 16 * MB);  // 6MB  [3072][1024] (q,k,v concat)
  __bf16* wpb  = (__bf16*)(ws + 22 * MB);  // 2MB
  __bf16* qb   = (__bf16*)(ws + 24 * MB);  // 16MB [B,H,T,HD]
  __bf16* kb   = qb + ((size_t)1 << 23);   // 16MB @40MB
  __bf16* vtb  = (__bf16*)(ws + 56 * MB);  // 16MB [B,H,HD,T] (written by gemm_qkv)
  __bf16* yb   = xb;                       // attn out overwrites x

  int n4 = (MM * CC) / 4;                  // 2097152
  cvt_f32_bf16<<<(n4 + 255) / 256, 256, 0, stream>>>(x, xb, n4);
  cvt_w4<<<dim3((CC * CC / 4) / 256, 4), 256, 0, stream>>>(
      Wq, Wk, Wv, Wp, wqkv, wpb);

  // fused QKV projection + V-transpose epilogue
  gemm_qkv<<<(MM / 256) * (3 * CC / 256), 512, 0, stream>>>(
      xb, wqkv, bq, bk, bv, qb, vtb);

  attn_fwd<<<NQT * BB * HH, 512, 0, stream>>>(qb, kb, vtb, pmask, yb);

  gemm_proj<<<(MM / 128) * (CC / 128), 256, 0, stream>>>(
      yb, wpb, bp, (float*)d_out, MM, CC, CC);
}

// Round 5
// 183.063 us; speedup vs baseline: 1.0692x; 1.0692x over previous
//
#include <hip/hip_runtime.h>
#include <hip/hip_bf16.h>
#include <math.h>
#include <stdint.h>

// Problem constants (reference: B=4, T=2048, C=1024, H=16, HD=64)
#define BB 4
#define TT 2048
#define CC 1024
#define HH 16
#define HD 64
#define MM (BB*TT)   // 8192
#define NQT2 16      // T / 128 q-tiles for attention (QBLK=128)
#define SCQ 0.180336878f   // (1/sqrt(HD)) * log2(e): Q pre-scale for exp2-domain softmax

using f32x2  = __attribute__((ext_vector_type(2))) float;
using f32x4  = __attribute__((ext_vector_type(4))) float;
using f32x16 = __attribute__((ext_vector_type(16))) float;
using i32x4  = __attribute__((ext_vector_type(4))) int;
using bf16x4 = __attribute__((ext_vector_type(4))) __bf16;
using bf16x8 = __attribute__((ext_vector_type(8))) __bf16;

__device__ __forceinline__ float fast_exp2(float x) {
  return __builtin_amdgcn_exp2f(x);   // v_exp_f32 (native exp2 on gfx950)
}

__device__ __forceinline__ int cvt_pk_bf16(float lo, float hi_) {
  int r;
  asm("v_cvt_pk_bf16_f32 %0, %1, %2" : "=v"(r) : "v"(lo), "v"(hi_));
  return r;   // low 16 = bf16(lo), high 16 = bf16(hi_)
}

__device__ __forceinline__ f32x2 max2(f32x2 a, f32x2 b) {
  return __builtin_elementwise_max(a, b);   // v_pk_max_f32
}

__device__ __forceinline__ void gload_lds16(const void* g, void* l) {
  __builtin_amdgcn_global_load_lds(
      (__attribute__((address_space(1))) void*)(void*)(g),
      (__attribute__((address_space(3))) void*)(l), 16, 0, 0);
}

// ---------------- fp32 -> bf16 converts ----------------
__global__ __launch_bounds__(256)
void cvt_f32_bf16(const float* __restrict__ s, __bf16* __restrict__ d, int n4) {
  int i = blockIdx.x * 256 + threadIdx.x;
  if (i >= n4) return;
  float4 v = ((const float4*)s)[i];
  bf16x4 o;
  o[0] = (__bf16)v.x; o[1] = (__bf16)v.y; o[2] = (__bf16)v.z; o[3] = (__bf16)v.w;
  *(bf16x4*)(d + (size_t)i * 4) = o;
}

// 4 weights in one launch; Wq scaled by SCQ and Wq/Wk/Wv written into the
// contiguous [3072][1024] concat buffer (order q,k,v); Wp separate.
__global__ __launch_bounds__(256)
void cvt_w4(const float* __restrict__ Wq, const float* __restrict__ Wk,
            const float* __restrict__ Wv, const float* __restrict__ Wp,
            __bf16* __restrict__ wqkv, __bf16* __restrict__ wpb) {
  int which = blockIdx.y;
  const float* s = which == 0 ? Wq : which == 1 ? Wk : which == 2 ? Wv : Wp;
  __bf16* d = which == 3 ? wpb : wqkv + (size_t)which * CC * CC;
  float sc = which == 0 ? SCQ : 1.f;
  int i = blockIdx.x * 256 + threadIdx.x;   // grid.x = (CC*CC/4)/256 = 1024
  float4 v = ((const float4*)s)[i];
  bf16x4 o;
  o[0] = (__bf16)(v.x * sc); o[1] = (__bf16)(v.y * sc);
  o[2] = (__bf16)(v.z * sc); o[3] = (__bf16)(v.w * sc);
  *(bf16x4*)(d + (size_t)i * 4) = o;
}

// ================== 8-phase 256x256 BK=64 QKV GEMM (m201 schedule) ==========
// C[8192,3072] = A[8192,1024] x Wqkv[3072,1024]^T + bias.
// proj 0/1 (Q,K): bf16 head-split [proj][B,H,T,HD] store.
// proj 2 (V): epilogue transposes the 256x256 tile through LDS (4 chunks of
// 64 cols) and writes Vt[bh][d][t] coalesced — replaces the transpose kernel.
#define WAITV6 asm volatile("s_waitcnt vmcnt(6)" ::: "memory")
#define WAITV4 asm volatile("s_waitcnt vmcnt(4)" ::: "memory")
#define WAITV0 asm volatile("s_waitcnt vmcnt(0)" ::: "memory")
#define WAITL0 asm volatile("s_waitcnt lgkmcnt(0)" ::: "memory")
#define BARR   __builtin_amdgcn_s_barrier()
#define SB0    __builtin_amdgcn_sched_barrier(0)
#define PRIO1  __builtin_amdgcn_s_setprio(1)
#define PRIO0  __builtin_amdgcn_s_setprio(0)

#define LDA_SET(buf, mq)                                                      \
  {                                                                           \
    const char* base_ = (const char*)&LA[buf][mq][0] + (wm * 64 + lq) * 128;  \
    _Pragma("unroll")                                                         \
    for (int m4 = 0; m4 < 4; ++m4)                                            \
      _Pragma("unroll")                                                       \
      for (int kk = 0; kk < 2; ++kk)                                          \
        a[m4 * 2 + kk] =                                                      \
            *(const bf16x8*)(base_ + m4 * 2048 + ((kk * 64 + g * 16) ^ swz)); \
  }

#define LDB_SET(buf, nq)                                                      \
  {                                                                           \
    const char* base_ = (const char*)&LB[buf][nq][0] + (wn * 32 + lq) * 128;  \
    _Pragma("unroll")                                                         \
    for (int n2 = 0; n2 < 2; ++n2)                                            \
      _Pragma("unroll")                                                       \
      for (int kk = 0; kk < 2; ++kk)                                          \
        b[nq][n2 * 2 + kk] =                                                  \
            *(const bf16x8*)(base_ + n2 * 2048 + ((kk * 64 + g * 16) ^ swz)); \
  }

#define STAGE_A(nbuf, h, tt)                                                  \
  {                                                                           \
    const char* s_ = Ag + ((size_t)((h)*128 + srow)) * 2048 + (tt)*128 + scol1; \
    gload_lds16(s_, (char*)&LA[nbuf][h][0] + so16);                           \
    gload_lds16(s_ + (size_t)64 * 2048, (char*)&LA[nbuf][h][0] + so16 + 8192);\
  }

#define STAGE_B(nbuf, h, tt)                                                  \
  {                                                                           \
    const char* s_ = Bg + ((size_t)((h)*128 + srow)) * 2048 + (tt)*128 + scol1; \
    gload_lds16(s_, (char*)&LB[nbuf][h][0] + so16);                           \
    gload_lds16(s_ + (size_t)64 * 2048, (char*)&LB[nbuf][h][0] + so16 + 8192);\
  }

#define MFMA_PH(mq, nq)                                                       \
  _Pragma("unroll")                                                           \
  for (int m4 = 0; m4 < 4; ++m4)                                              \
    _Pragma("unroll")                                                         \
    for (int n2 = 0; n2 < 2; ++n2)                                            \
      _Pragma("unroll")                                                       \
      for (int kk = 0; kk < 2; ++kk)                                          \
        acc[mq][m4][nq][n2] = __builtin_amdgcn_mfma_f32_16x16x32_bf16(        \
            a[m4 * 2 + kk], b[nq][n2 * 2 + kk], acc[mq][m4][nq][n2], 0, 0, 0);

__global__ __launch_bounds__(512, 2)
void gemm_qkv(const __bf16* __restrict__ A, const __bf16* __restrict__ Bm,
              const float* __restrict__ b0, const float* __restrict__ b1,
              const float* __restrict__ b2, __bf16* __restrict__ out,
              __bf16* __restrict__ vt) {
  __shared__ __bf16 LA[2][2][128 * 64];   // [K-tile parity][half][128 x 64]
  __shared__ __bf16 LB[2][2][128 * 64];   // 128 KiB total
  const int tid = threadIdx.x, wid = tid >> 6, lane = tid & 63;
  const int g = lane >> 4, lq = lane & 15;
  const int wm = wid >> 2, wn = wid & 3;             // 2M x 4N waves
  const int bm = blockIdx.x / 12, bn = blockIdx.x % 12;
  const int brow = bm << 8, bcol = bn << 8;
  const int swz = (lq & 7) << 4;

  // staging geometry: thread stages 2x16B chunks per half-tile
  const int srow = tid >> 3, so16 = tid * 16;
  const int scol1 = ((tid & 7) << 4) ^ ((srow & 7) << 4);  // inverse-swizzled src col
  const char* Ag = (const char*)A + (size_t)brow * 2048;   // K=1024 -> 2048B rows
  const char* Bg = (const char*)Bm + (size_t)bcol * 2048;

  f32x4 acc[2][4][2][2] = {};
  bf16x8 a[8], b[2][4];

  // prologue: 7 halves = tile0 {A0,B0,B1,A1} + tile1 {A0,B0,B1}
  STAGE_A(0, 0, 0); STAGE_B(0, 0, 0); STAGE_B(0, 1, 0); STAGE_A(0, 1, 0);
  STAGE_A(1, 0, 1); STAGE_B(1, 0, 1); STAGE_B(1, 1, 1);
  WAITV6; BARR;

#pragma unroll 1
  for (int t = 0; t < 8; ++t) {
    const bool s2 = (t < 7);
    const int k1 = 2 * t + 1, k2 = 2 * t + 2, k3 = 2 * t + 3;
    // ---- p1: tile 2t (buf0) quad (0,0); stage A1(2t+1) ----
    LDA_SET(0, 0); LDB_SET(0, 0);
    STAGE_A(1, 1, k1);
    BARR; WAITL0; SB0;
    PRIO1; MFMA_PH(0, 0); PRIO0; BARR;
    // ---- p2: quad (0,1); stage A0(2t+2) ----
    LDB_SET(0, 1);
    if (s2) STAGE_A(0, 0, k2);
    BARR; WAITL0; SB0;
    PRIO1; MFMA_PH(0, 1); PRIO0; BARR;
    // ---- p3: quad (1,1); stage B0(2t+2) ----
    LDA_SET(0, 1);
    if (s2) STAGE_B(0, 0, k2);
    BARR; WAITL0; SB0;
    PRIO1; MFMA_PH(1, 1); PRIO0; BARR;
    // ---- p4: quad (1,0); stage B1(2t+2); counted vmcnt ----
    if (s2) { STAGE_B(0, 1, k2); WAITV6; } else { WAITV0; }
    BARR; SB0;
    PRIO1; MFMA_PH(1, 0); PRIO0; BARR;
    // ---- p5: tile 2t+1 (buf1) quad (0,0); stage A1(2t+2) ----
    LDA_SET(1, 0); LDB_SET(1, 0);
    if (s2) STAGE_A(0, 1, k2);
    BARR; WAITL0; SB0;
    PRIO1; MFMA_PH(0, 0); PRIO0; BARR;
    // ---- p6: quad (0,1); stage A0(2t+3) ----
    LDB_SET(1, 1);
    if (s2) STAGE_A(1, 0, k3);
    BARR; WAITL0; SB0;
    PRIO1; MFMA_PH(0, 1); PRIO0; BARR;
    // ---- p7: quad (1,1); stage B0(2t+3) ----
    LDA_SET(1, 1);
    if (s2) STAGE_B(1, 0, k3);
    BARR; WAITL0; SB0;
    PRIO1; MFMA_PH(1, 1); PRIO0; BARR;
    // ---- p8: quad (1,0); stage B1(2t+3); counted vmcnt ----
    if (s2) { STAGE_B(1, 1, k3); WAITV6; }
    BARR; SB0;
    PRIO1; MFMA_PH(1, 0); PRIO0; BARR;
  }

  const int proj = bn >> 2;   // uniform per block (256 | 1024)
  if (proj < 2) {
    // epilogue: bias + bf16 head-split store [proj][B,H,T,HD]
    const float* bias = proj == 0 ? b0 : b1;
    const float bsc = proj == 0 ? SCQ : 1.f;
#pragma unroll
    for (int mq = 0; mq < 2; ++mq)
#pragma unroll
      for (int nq = 0; nq < 2; ++nq)
#pragma unroll
        for (int n2 = 0; n2 < 2; ++n2) {
          int col = bcol + nq * 128 + wn * 32 + n2 * 16 + lq;
          int cw = col & (CC - 1);
          float bb = bias[cw] * bsc;
          int h_ = cw >> 6, d_ = cw & (HD - 1);
#pragma unroll
          for (int m4 = 0; m4 < 4; ++m4) {
            int row0 = brow + mq * 128 + wm * 64 + m4 * 16 + g * 4;
#pragma unroll
            for (int i = 0; i < 4; ++i) {
              int row = row0 + i;
              int b_ = row >> 11, t_ = row & (TT - 1);
              out[((size_t)proj << 23) +
                  ((((size_t)b_ * HH + h_) * TT + t_) << 6) + d_] =
                  (__bf16)(acc[mq][m4][nq][n2][i] + bb);
            }
          }
        }
  } else {
    // V: transpose 256x256 tile through LDS (4 chunks of 64 cols = 1 head
    // each) and write Vt[bh][d][t] coalesced. LDS main buffers are free.
    __bf16* lt = (__bf16*)&LA[0][0][0];          // [64 cols][264 rows]
    const int cv0 = (bn & 3) << 8;               // col offset within V region
    const int b_ = brow >> 11, t0 = brow & (TT - 1);
    const int hbase = (bn & 3) << 2;
    const int rd_d = tid >> 3, rd_tb = (tid & 7) << 5;
#pragma unroll
    for (int cc = 0; cc < 4; ++cc) {
      if ((wn >> 1) == (cc & 1)) {               // 4 writer waves per chunk
#pragma unroll
        for (int n2 = 0; n2 < 2; ++n2) {
          int c = ((wn & 1) << 5) + (n2 << 4) + lq;
          float bb = b2[cv0 + (cc << 6) + c];
#pragma unroll
          for (int mq = 0; mq < 2; ++mq)
#pragma unroll
            for (int m4 = 0; m4 < 4; ++m4) {
              int r = (mq << 7) + (wm << 6) + (m4 << 4) + (g << 2);
              bf16x4 pk;
#pragma unroll
              for (int i = 0; i < 4; ++i)
                pk[i] = (__bf16)(acc[mq][m4][cc >> 1][n2][i] + bb);
              *(bf16x4*)(lt + c * 264 + r) = pk;
            }
        }
      }
      __syncthreads();
      // readers: all 512 threads; d = tid>>3, 32 t-elems each
      __bf16* dst = vt + (((size_t)((b_ * HH + hbase + cc) * HD + rd_d)) << 11)
                       + t0 + rd_tb;
      const __bf16* srcl = lt + rd_d * 264 + rd_tb;
#pragma unroll
      for (int j = 0; j < 4; ++j)
        *(bf16x8*)(dst + j * 8) = *(const bf16x8*)(srcl + j * 8);
      __syncthreads();
    }
  }
}

// ---------------- proj GEMM (m97 structure): fp32 out ----------------
__global__ __launch_bounds__(256, 2)
void gemm_proj(const __bf16* __restrict__ A, const __bf16* __restrict__ Bm,
               const float* __restrict__ bias, float* __restrict__ out,
               int M, int N, int K) {
  __shared__ __bf16 As[128 * 32];
  __shared__ __bf16 Bs[128 * 32];
  const int tid = threadIdx.x;
  const int wid = tid >> 6, lane = tid & 63;
  const int g = lane >> 4, lq = lane & 15;
  const int nbn = N >> 7;
  const int brow = (blockIdx.x / nbn) << 7;
  const int bcol = (blockIdx.x % nbn) << 7;
  const int wr = (wid >> 1) << 6, wc = (wid & 1) << 6;

  f32x4 acc[4][4] = {};

  const int o0 = wid * 2048 + lane * 16;
  for (int kt = 0; kt < K; kt += 32) {
    __syncthreads();
#pragma unroll
    for (int j = 0; j < 2; ++j) {
      int o = o0 + j * 1024;
      int row = o >> 6, colb = o & 63;
      gload_lds16((const char*)A + ((size_t)(brow + row) * K + kt) * 2 + colb,
                  (char*)As + o);
      gload_lds16((const char*)Bm + ((size_t)(bcol + row) * K + kt) * 2 + colb,
                  (char*)Bs + o);
    }
    __syncthreads();
    bf16x8 av[4], bv[4];
#pragma unroll
    for (int m = 0; m < 4; ++m)
      av[m] = *(const bf16x8*)(As + (wr + m * 16 + lq) * 32 + g * 8);
#pragma unroll
    for (int n = 0; n < 4; ++n)
      bv[n] = *(const bf16x8*)(Bs + (wc + n * 16 + lq) * 32 + g * 8);
#pragma unroll
    for (int m = 0; m < 4; ++m)
#pragma unroll
      for (int n = 0; n < 4; ++n)
        acc[m][n] = __builtin_amdgcn_mfma_f32_16x16x32_bf16(av[m], bv[n], acc[m][n], 0, 0, 0);
  }

#pragma unroll
  for (int m = 0; m < 4; ++m) {
#pragma unroll
    for (int n = 0; n < 4; ++n) {
      int col = bcol + wc + n * 16 + lq;
      float bb = bias[col];
      int row0 = brow + wr + m * 16 + g * 4;
#pragma unroll
      for (int i = 0; i < 4; ++i)
        out[(size_t)(row0 + i) * N + col] = acc[m][n][i] + bb;
    }
  }
}

// ---------------- Flash attention v5b (causal + padding mask) ----------------
// grid 1024 = 16 q-tiles x 64 bh, 256 threads = 4 waves x 32 q-rows (QBLK=128).
// 32x32x16 MFMA, swapped QK^T, split-half S (one f32x16 live).
// v5b = v5 with the P-exchange REVERTED to the harness-validated v3/v4
// select+shfl_xor form. (v5's 4 dup-shuffles gave every lane {A(lo),B(hi)} —
// uniform mix — but lo lanes need A-pairs of BOTH halves and hi lanes B-pairs
// of BOTH halves. Half-dependent content needs the select structure.)
// Other v5 features kept:
//  * 4-wave blocks (grid 1024), Latin-square qi map, 4-wave barrier scope.
//  * TRIPLE buffer + ONE barrier/tile, counted vmcnt (WAITV4 steady state),
//    prefetch distance 2 tiles; pm-mask hoisted to one block-level check.
//  * VALU diet: MFMA C = persistent zero vector; packed-f32 max/sub/sum trees.
// C/D layout (m74/m101): col = lane&31, row = (r&3) + 8*(r>>2) + 4*(lane>>5).
__global__ __launch_bounds__(256, 3)
void attn_fwd(const __bf16* __restrict__ Q, const __bf16* __restrict__ K,
              const __bf16* __restrict__ Vt, const int* __restrict__ pm,
              __bf16* __restrict__ Y) {
  __shared__ __bf16 Ks[3][64 * 64];   // 24 KiB
  __shared__ __bf16 Vs[3][64 * 64];   // 24 KiB
  __shared__ int flg;
  const int tid = threadIdx.x, wid = tid >> 6, lane = tid & 63;
  const int l31 = lane & 31, hi = lane >> 5;
  const int bx = blockIdx.x;
  const int bh = bx & 63, jj = bx >> 6;          // jj 0..15
  // Latin-square qi map: qi = 4*(jj>>2) + ((jj + (jj>>2)) & 3).
  // Bijective; each class {j, j+4, j+8, j+12} sums qi to 30 -> balanced for
  // round-robin block->CU groupings.
  const int qi = 4 * (jj >> 2) + ((jj + (jj >> 2)) & 3);
  const int b_ = bh >> 4, h_ = bh & 15;
  const __bf16* Qb = Q + (size_t)bh * TT * HD;
  const __bf16* Kb = K + (size_t)bh * TT * HD;
  const __bf16* Vb = Vt + (size_t)bh * HD * TT;
  const int* pmb = pm + b_ * TT;

  const int so = tid * 16;                 // 16B chunk, 0..4080
  const int srow = tid >> 3;               // 0..31
  const int scol = (so & 127) ^ ((srow & 7) << 4);   // inverse-swizzled src col

  const int q0 = qi << 7;
  const int qw = q0 + wid * 32;            // this wave's 32 q-rows
  const int ntiles = 2 * qi + 2;           // >= 2 always
  const int sw0 = (l31 & 7) << 4;

  // Q fragments: lane holds Q[qw+l31][16s + 8hi .. +7], s=0..3
  bf16x8 qf[4];
#pragma unroll
  for (int s = 0; s < 4; ++s)
    qf[s] = *(const bf16x8*)(Qb + (size_t)(qw + l31) * HD + s * 16 + hi * 8);
  SB0;   // pin qf loads above the staging issues (vmcnt accounting)

  // padding-mask block check: 256 threads x 2 int4 cover the 2048-int pm row
  int4 pa4 = ((const int4*)pmb)[tid];
  int4 pb4 = ((const int4*)pmb)[tid + 256];
  bool okp = pa4.x && pa4.y && pa4.z && pa4.w &&
             pb4.x && pb4.y && pb4.z && pb4.w;
  if (tid == 0) flg = 1;
  __syncthreads();
  if (!okp) flg = 0;                       // benign race (all writers store 0)

  // prologue: stage tiles 0,1 into bufs 0,1 (4 gloads each: 2 K + 2 V)
#pragma unroll
  for (int n = 0; n < 2; ++n) {
    char* kd = (char*)&Ks[0][0] + n * 8192 + so;
    char* vd = (char*)&Vs[0][0] + n * 8192 + so;
#pragma unroll
    for (int j = 0; j < 2; ++j) {
      gload_lds16((const char*)Kb + (size_t)(n * 64 + srow + 32 * j) * 128 + scol,
                  kd + j * 4096);
      gload_lds16((const char*)Vb + (size_t)(srow + 32 * j) * (TT * 2) +
                      n * 128 + scol,
                  vd + j * 4096);
    }
  }
  __syncthreads();                         // tiles 0,1 staged; flg final
  const bool allones = (flg != 0);

  f32x16 o0 = {}, o1 = {};                 // O[q=crow(r,hi)][d = l31 | 32+l31]
  f32x16 vzero = {};                       // persistent zero C-operand
  float lsum = 0.f;                        // partial row-sum (this lane-half)
  float m = -INFINITY;                     // running max for q = qw+l31

  int cur = 0;
#pragma unroll 1
  for (int t = 0; t < ntiles; ++t) {
    const int kv0 = t << 6;
    // ---- wait for tile t (counted; stage(t+1) stays in flight) ----
    if (t + 1 < ntiles) { WAITV4; } else { WAITV0; }
    BARR; SB0;   // all waves: tile t ready AND tile t-1 reads finished
    // ---- issue stage(t+2) into buf[(t+2)%3] (held tile t-1) ----
    if (t + 2 < ntiles) {
      int stb = cur + 2; if (stb >= 3) stb -= 3;
      char* kd = (char*)&Ks[0][0] + stb * 8192 + so;
      char* vd = (char*)&Vs[0][0] + stb * 8192 + so;
      const size_t nk = (size_t)(kv0 + 128);
#pragma unroll
      for (int j = 0; j < 2; ++j) {
        gload_lds16((const char*)Kb + (nk + srow + 32 * j) * 128 + scol,
                    kd + j * 4096);
        gload_lds16((const char*)Vb + (size_t)(srow + 32 * j) * (TT * 2) +
                        nk * 2 + scol,
                    vd + j * 4096);
      }
    }

    unsigned long long bits = ~0ull;
    if (__builtin_expect(!allones, 0))     // rare slow path
      bits = __ballot(pmb[kv0 + lane] != 0);

    if (kv0 <= qw + 31) {                  // wave-uniform participation
      const char* VsC = (const char*)&Vs[0][0] + cur * 8192;

#pragma unroll
      for (int h = 0; h < 2; ++h) {
        const int kvh = kv0 + 32 * h;
        if (kvh <= qw + 31) {              // wave-uniform per-half gate
          // ---- QK^T (swapped): S[kvh+crow][q=l31] ----
          const char* KsC =
              (const char*)&Ks[0][0] + cur * 8192 + (32 * h + l31) * 128;
          f32x16 S;
          __builtin_amdgcn_s_setprio(1);
          {
            bf16x8 k0 = *(const bf16x8*)(KsC + ((16 * hi) ^ sw0));
            S = __builtin_amdgcn_mfma_f32_32x32x16_bf16(k0, qf[0], vzero, 0, 0, 0);
          }
#pragma unroll
          for (int s = 1; s < 4; ++s) {
            bf16x8 kf = *(const bf16x8*)(KsC + ((32 * s + 16 * hi) ^ sw0));
            S = __builtin_amdgcn_mfma_f32_32x32x16_bf16(kf, qf[s], S, 0, 0, 0);
          }
          __builtin_amdgcn_s_setprio(0);

          // ---- masks ----
          if (__builtin_expect(bits != ~0ull, 0)) {   // padding (rare)
#pragma unroll
            for (int r = 0; r < 16; ++r) {
              const int c = (r & 3) + 8 * (r >> 2);
              if (!((bits >> (32 * h + c + 4 * hi)) & 1ull)) S[r] = -INFINITY;
            }
          }
          if (kvh + 31 > qw) {             // causal diag (wave-uniform)
            const int thr = qw + l31 - kvh - 4 * hi;
#pragma unroll
            for (int r = 0; r < 16; ++r) {
              const int c = (r & 3) + 8 * (r >> 2);
              S[r] = (c <= thr) ? S[r] : -INFINITY;
            }
          }

          // ---- row max via packed-f32 tree + defer-rescale check ----
          f32x2 x0 = {S[0], S[1]},  x1 = {S[2], S[3]};
          f32x2 x2 = {S[4], S[5]},  x3 = {S[6], S[7]};
          f32x2 x4 = {S[8], S[9]},  x5 = {S[10], S[11]};
          f32x2 x6 = {S[12], S[13]}, x7 = {S[14], S[15]};
          x0 = max2(x0, x4); x1 = max2(x1, x5);
          x2 = max2(x2, x6); x3 = max2(x3, x7);
          x0 = max2(x0, x2); x1 = max2(x1, x3);
          x0 = max2(x0, x1);
          float pmax = fmaxf(x0[0], x0[1]);
          if (!__all(pmax <= m + 8.f)) {
            float nm = fmaxf(pmax, __shfl_xor(pmax, 32));  // full row max
            float mn = fmaxf(m, nm);
            float c = fast_exp2(m - mn);
            m = mn;
            lsum *= c;
#pragma unroll
            for (int r = 0; r < 16; ++r) {
              float cr = __shfl(c, (r & 3) + 8 * (r >> 2) + 4 * hi);
              o0[r] *= cr;
              o1[r] *= cr;
            }
          }

          // ---- P = exp2(S - m) (packed sub, trans exp) ----
          const f32x2 mm = {m, m};
#pragma unroll
          for (int r = 0; r < 16; r += 2) {
            f32x2 u = {S[r], S[r + 1]};
            u -= mm;                      // v_pk_add_f32
            S[r] = fast_exp2(u[0]);
            S[r + 1] = fast_exp2(u[1]);
          }
          // ---- in-lane row-sum via packed-f32 tree ----
          {
            f32x2 u0 = {S[0], S[1]},  u1 = {S[2], S[3]};
            f32x2 u2 = {S[4], S[5]},  u3 = {S[6], S[7]};
            f32x2 u4 = {S[8], S[9]},  u5 = {S[10], S[11]};
            f32x2 u6 = {S[12], S[13]}, u7 = {S[14], S[15]};
            u0 += u4; u1 += u5; u2 += u6; u3 += u7;
            u0 += u2; u1 += u3;
            u0 += u1;
            lsum += u0[0] + u0[1];
          }

          // ---- PV: build A-fragments (validated select+shfl_xor exchange) ----
          __builtin_amdgcn_s_setprio(1);
#pragma unroll
          for (int s = 0; s < 2; ++s) {
            int A0 = cvt_pk_bf16(S[8 * s + 0], S[8 * s + 1]);
            int A1 = cvt_pk_bf16(S[8 * s + 2], S[8 * s + 3]);
            int B0 = cvt_pk_bf16(S[8 * s + 4], S[8 * s + 5]);
            int B1 = cvt_pk_bf16(S[8 * s + 6], S[8 * s + 7]);
            // exchange across lane+-32: lo lanes need A-pairs of BOTH halves,
            // hi lanes need B-pairs of BOTH halves.
            int s0 = hi ? A0 : B0, s1 = hi ? A1 : B1;
            int e0 = __shfl_xor(s0, 32), e1 = __shfl_xor(s1, 32);
            i32x4 wv;
            wv[0] = hi ? e0 : A0;
            wv[1] = hi ? e1 : A1;
            wv[2] = hi ? B0 : e0;
            wv[3] = hi ? B1 : e1;
            bf16x8 pa = __builtin_bit_cast(bf16x8, wv);
            const int co = 64 * h + 32 * s + 16 * hi;   // kv byte offset
            bf16x8 v0 = *(const bf16x8*)(VsC + l31 * 128 + (co ^ sw0));
            bf16x8 v1 = *(const bf16x8*)(VsC + (32 + l31) * 128 + (co ^ sw0));
            o0 = __builtin_amdgcn_mfma_f32_32x32x16_bf16(pa, v0, o0, 0, 0, 0);
            o1 = __builtin_amdgcn_mfma_f32_32x32x16_bf16(pa, v1, o1, 0, 0, 0);
          }
          __builtin_amdgcn_s_setprio(0);
        }
      }
    }
    SB0;   // pin this tile's LDS reads above next iteration's barrier
    cur = (cur == 2) ? 0 : cur + 1;
  }

  // epilogue: combine lane-halves' row-sums, normalize + store
  float linv = 1.f / (lsum + __shfl_xor(lsum, 32));
#pragma unroll
  for (int r = 0; r < 16; ++r) {
    const int crow = (r & 3) + 8 * (r >> 2) + 4 * hi;
    float ir = __shfl(linv, crow);
    const int qrow = qw + crow;
    __bf16* yp = Y + ((size_t)(b_ * TT + qrow)) * CC + h_ * HD + l31;
    yp[0]  = (__bf16)(o0[r] * ir);
    yp[32] = (__bf16)(o1[r] * ir);
  }
}

// ---------------- launch ----------------
extern "C" void kernel_launch(void* const* d_in, const int* in_sizes, int n_in,
                              void* d_out, int out_size, void* d_ws, size_t ws_size,
                              hipStream_t stream) {
  (void)in_sizes; (void)n_in; (void)out_size; (void)ws_size;
  const float* x  = (const float*)d_in[0];
  const float* Wk = (const float*)d_in[1];
  const float* bk = (const float*)d_in[2];
  const float* Wq = (const float*)d_in[3];
  const float* bq = (const float*)d_in[4];
  const float* Wv = (const float*)d_in[5];
  const float* bv = (const float*)d_in[6];
  const float* Wp = (const float*)d_in[7];
  const float* bp = (const float*)d_in[8];
  const int* pmask = (const int*)d_in[9];

  char* ws = (char*)d_ws;
  const size_t MB = 1024 * 1024;
  __bf16* xb   = (__bf16*)(ws);            // 16MB; reused as attn-out y
  __bf16* wqkv = (__bf16*)(ws + 16 * MB);  // 6MB  [3072][1024] (q,k,v concat)
  __bf16* wpb  = (__bf16*)(ws + 22 * MB);  // 2MB
  __bf16* qb   = (__bf16*)(ws + 24 * MB);  // 16MB [B,H,T,HD]
  __bf16* kb   = qb + ((size_t)1 << 23);   // 16MB @40MB
  __bf16* vtb  = (__bf16*)(ws + 56 * MB);  // 16MB [B,H,HD,T] (written by gemm_qkv)
  __bf16* yb   = xb;                       // attn out overwrites x

  int n4 = (MM * CC) / 4;                  // 2097152
  cvt_f32_bf16<<<(n4 + 255) / 256, 256, 0, stream>>>(x, xb, n4);
  cvt_w4<<<dim3((CC * CC / 4) / 256, 4), 256, 0, stream>>>(
      Wq, Wk, Wv, Wp, wqkv, wpb);

  // fused QKV projection + V-transpose epilogue
  gemm_qkv<<<(MM / 256) * (3 * CC / 256), 512, 0, stream>>>(
      xb, wqkv, bq, bk, bv, qb, vtb);

  attn_fwd<<<NQT2 * BB * HH, 256, 0, stream>>>(qb, kb, vtb, pmask, yb);

  gemm_proj<<<(MM / 128) * (CC / 128), 256, 0, stream>>>(
      yb, wpb, bp, (float*)d_out, MM, CC, CC);
}

// Round 6
// 173.976 us; speedup vs baseline: 1.1250x; 1.0522x over previous
//
#include <hip/hip_runtime.h>
#include <hip/hip_bf16.h>
#include <math.h>
#include <stdint.h>

// Problem constants (reference: B=4, T=2048, C=1024, H=16, HD=64)
#define BB 4
#define TT 2048
#define CC 1024
#define HH 16
#define HD 64
#define MM (BB*TT)   // 8192
#define NQT2 16      // T / 128 q-tiles for attention (QBLK=128)
#define SCQ 0.180336878f   // (1/sqrt(HD)) * log2(e): Q pre-scale for exp2-domain softmax

using f32x2  = __attribute__((ext_vector_type(2))) float;
using f32x4  = __attribute__((ext_vector_type(4))) float;
using f32x16 = __attribute__((ext_vector_type(16))) float;
using i32x4  = __attribute__((ext_vector_type(4))) int;
using bf16x4 = __attribute__((ext_vector_type(4))) __bf16;
using bf16x8 = __attribute__((ext_vector_type(8))) __bf16;

__device__ __forceinline__ float fast_exp2(float x) {
  return __builtin_amdgcn_exp2f(x);   // v_exp_f32 (native exp2 on gfx950)
}

__device__ __forceinline__ int cvt_pk_bf16(float lo, float hi_) {
  int r;
  asm("v_cvt_pk_bf16_f32 %0, %1, %2" : "=v"(r) : "v"(lo), "v"(hi_));
  return r;   // low 16 = bf16(lo), high 16 = bf16(hi_)
}

__device__ __forceinline__ f32x2 max2(f32x2 a, f32x2 b) {
  return __builtin_elementwise_max(a, b);   // v_pk_max_f32
}

__device__ __forceinline__ void gload_lds16(const void* g, void* l) {
  __builtin_amdgcn_global_load_lds(
      (__attribute__((address_space(1))) void*)(void*)(g),
      (__attribute__((address_space(3))) void*)(l), 16, 0, 0);
}

// ---------------- fp32 -> bf16 converts ----------------
__global__ __launch_bounds__(256)
void cvt_f32_bf16(const float* __restrict__ s, __bf16* __restrict__ d, int n4) {
  int i = blockIdx.x * 256 + threadIdx.x;
  if (i >= n4) return;
  float4 v = ((const float4*)s)[i];
  bf16x4 o;
  o[0] = (__bf16)v.x; o[1] = (__bf16)v.y; o[2] = (__bf16)v.z; o[3] = (__bf16)v.w;
  *(bf16x4*)(d + (size_t)i * 4) = o;
}

// 4 weights in one launch; Wq scaled by SCQ and Wq/Wk/Wv written into the
// contiguous [3072][1024] concat buffer (order q,k,v); Wp separate.
__global__ __launch_bounds__(256)
void cvt_w4(const float* __restrict__ Wq, const float* __restrict__ Wk,
            const float* __restrict__ Wv, const float* __restrict__ Wp,
            __bf16* __restrict__ wqkv, __bf16* __restrict__ wpb) {
  int which = blockIdx.y;
  const float* s = which == 0 ? Wq : which == 1 ? Wk : which == 2 ? Wv : Wp;
  __bf16* d = which == 3 ? wpb : wqkv + (size_t)which * CC * CC;
  float sc = which == 0 ? SCQ : 1.f;
  int i = blockIdx.x * 256 + threadIdx.x;   // grid.x = (CC*CC/4)/256 = 1024
  float4 v = ((const float4*)s)[i];
  bf16x4 o;
  o[0] = (__bf16)(v.x * sc); o[1] = (__bf16)(v.y * sc);
  o[2] = (__bf16)(v.z * sc); o[3] = (__bf16)(v.w * sc);
  *(bf16x4*)(d + (size_t)i * 4) = o;
}

// ================== 8-phase 256x256 BK=64 QKV GEMM (m201 schedule) ==========
// C[8192,3072] = A[8192,1024] x Wqkv[3072,1024]^T + bias.
// proj 0/1 (Q,K): bf16 head-split [proj][B,H,T,HD] store.
// proj 2 (V): epilogue transposes the 256x256 tile through LDS (4 chunks of
// 64 cols) and writes Vt[bh][d][t] coalesced — replaces the transpose kernel.
#define WAITV6 asm volatile("s_waitcnt vmcnt(6)" ::: "memory")
#define WAITV0 asm volatile("s_waitcnt vmcnt(0)" ::: "memory")
#define WAITL0 asm volatile("s_waitcnt lgkmcnt(0)" ::: "memory")
#define BARR   __builtin_amdgcn_s_barrier()
#define SB0    __builtin_amdgcn_sched_barrier(0)
#define PRIO1  __builtin_amdgcn_s_setprio(1)
#define PRIO0  __builtin_amdgcn_s_setprio(0)

#define LDA_SET(buf, mq)                                                      \
  {                                                                           \
    const char* base_ = (const char*)&LA[buf][mq][0] + (wm * 64 + lq) * 128;  \
    _Pragma("unroll")                                                         \
    for (int m4 = 0; m4 < 4; ++m4)                                            \
      _Pragma("unroll")                                                       \
      for (int kk = 0; kk < 2; ++kk)                                          \
        a[m4 * 2 + kk] =                                                      \
            *(const bf16x8*)(base_ + m4 * 2048 + ((kk * 64 + g * 16) ^ swz)); \
  }

#define LDB_SET(buf, nq)                                                      \
  {                                                                           \
    const char* base_ = (const char*)&LB[buf][nq][0] + (wn * 32 + lq) * 128;  \
    _Pragma("unroll")                                                         \
    for (int n2 = 0; n2 < 2; ++n2)                                            \
      _Pragma("unroll")                                                       \
      for (int kk = 0; kk < 2; ++kk)                                          \
        b[nq][n2 * 2 + kk] =                                                  \
            *(const bf16x8*)(base_ + n2 * 2048 + ((kk * 64 + g * 16) ^ swz)); \
  }

#define STAGE_A(nbuf, h, tt)                                                  \
  {                                                                           \
    const char* s_ = Ag + ((size_t)((h)*128 + srow)) * 2048 + (tt)*128 + scol1; \
    gload_lds16(s_, (char*)&LA[nbuf][h][0] + so16);                           \
    gload_lds16(s_ + (size_t)64 * 2048, (char*)&LA[nbuf][h][0] + so16 + 8192);\
  }

#define STAGE_B(nbuf, h, tt)                                                  \
  {                                                                           \
    const char* s_ = Bg + ((size_t)((h)*128 + srow)) * 2048 + (tt)*128 + scol1; \
    gload_lds16(s_, (char*)&LB[nbuf][h][0] + so16);                           \
    gload_lds16(s_ + (size_t)64 * 2048, (char*)&LB[nbuf][h][0] + so16 + 8192);\
  }

#define MFMA_PH(mq, nq)                                                       \
  _Pragma("unroll")                                                           \
  for (int m4 = 0; m4 < 4; ++m4)                                              \
    _Pragma("unroll")                                                         \
    for (int n2 = 0; n2 < 2; ++n2)                                            \
      _Pragma("unroll")                                                       \
      for (int kk = 0; kk < 2; ++kk)                                          \
        acc[mq][m4][nq][n2] = __builtin_amdgcn_mfma_f32_16x16x32_bf16(        \
            a[m4 * 2 + kk], b[nq][n2 * 2 + kk], acc[mq][m4][nq][n2], 0, 0, 0);

__global__ __launch_bounds__(512, 2)
void gemm_qkv(const __bf16* __restrict__ A, const __bf16* __restrict__ Bm,
              const float* __restrict__ b0, const float* __restrict__ b1,
              const float* __restrict__ b2, __bf16* __restrict__ out,
              __bf16* __restrict__ vt) {
  __shared__ __bf16 LA[2][2][128 * 64];   // [K-tile parity][half][128 x 64]
  __shared__ __bf16 LB[2][2][128 * 64];   // 128 KiB total
  const int tid = threadIdx.x, wid = tid >> 6, lane = tid & 63;
  const int g = lane >> 4, lq = lane & 15;
  const int wm = wid >> 2, wn = wid & 3;             // 2M x 4N waves
  const int bm = blockIdx.x / 12, bn = blockIdx.x % 12;
  const int brow = bm << 8, bcol = bn << 8;
  const int swz = (lq & 7) << 4;

  // staging geometry: thread stages 2x16B chunks per half-tile
  const int srow = tid >> 3, so16 = tid * 16;
  const int scol1 = ((tid & 7) << 4) ^ ((srow & 7) << 4);  // inverse-swizzled src col
  const char* Ag = (const char*)A + (size_t)brow * 2048;   // K=1024 -> 2048B rows
  const char* Bg = (const char*)Bm + (size_t)bcol * 2048;

  f32x4 acc[2][4][2][2] = {};
  bf16x8 a[8], b[2][4];

  // prologue: 7 halves = tile0 {A0,B0,B1,A1} + tile1 {A0,B0,B1}
  STAGE_A(0, 0, 0); STAGE_B(0, 0, 0); STAGE_B(0, 1, 0); STAGE_A(0, 1, 0);
  STAGE_A(1, 0, 1); STAGE_B(1, 0, 1); STAGE_B(1, 1, 1);
  WAITV6; BARR;

#pragma unroll 1
  for (int t = 0; t < 8; ++t) {
    const bool s2 = (t < 7);
    const int k1 = 2 * t + 1, k2 = 2 * t + 2, k3 = 2 * t + 3;
    // ---- p1: tile 2t (buf0) quad (0,0); stage A1(2t+1) ----
    LDA_SET(0, 0); LDB_SET(0, 0);
    STAGE_A(1, 1, k1);
    BARR; WAITL0; SB0;
    PRIO1; MFMA_PH(0, 0); PRIO0; BARR;
    // ---- p2: quad (0,1); stage A0(2t+2) ----
    LDB_SET(0, 1);
    if (s2) STAGE_A(0, 0, k2);
    BARR; WAITL0; SB0;
    PRIO1; MFMA_PH(0, 1); PRIO0; BARR;
    // ---- p3: quad (1,1); stage B0(2t+2) ----
    LDA_SET(0, 1);
    if (s2) STAGE_B(0, 0, k2);
    BARR; WAITL0; SB0;
    PRIO1; MFMA_PH(1, 1); PRIO0; BARR;
    // ---- p4: quad (1,0); stage B1(2t+2); counted vmcnt ----
    if (s2) { STAGE_B(0, 1, k2); WAITV6; } else { WAITV0; }
    BARR; SB0;
    PRIO1; MFMA_PH(1, 0); PRIO0; BARR;
    // ---- p5: tile 2t+1 (buf1) quad (0,0); stage A1(2t+2) ----
    LDA_SET(1, 0); LDB_SET(1, 0);
    if (s2) STAGE_A(0, 1, k2);
    BARR; WAITL0; SB0;
    PRIO1; MFMA_PH(0, 0); PRIO0; BARR;
    // ---- p6: quad (0,1); stage A0(2t+3) ----
    LDB_SET(1, 1);
    if (s2) STAGE_A(1, 0, k3);
    BARR; WAITL0; SB0;
    PRIO1; MFMA_PH(0, 1); PRIO0; BARR;
    // ---- p7: quad (1,1); stage B0(2t+3) ----
    LDA_SET(1, 1);
    if (s2) STAGE_B(1, 0, k3);
    BARR; WAITL0; SB0;
    PRIO1; MFMA_PH(1, 1); PRIO0; BARR;
    // ---- p8: quad (1,0); stage B1(2t+3); counted vmcnt ----
    if (s2) { STAGE_B(1, 1, k3); WAITV6; }
    BARR; SB0;
    PRIO1; MFMA_PH(1, 0); PRIO0; BARR;
  }

  const int proj = bn >> 2;   // uniform per block (256 | 1024)
  if (proj < 2) {
    // epilogue: bias + bf16 head-split store [proj][B,H,T,HD]
    const float* bias = proj == 0 ? b0 : b1;
    const float bsc = proj == 0 ? SCQ : 1.f;
#pragma unroll
    for (int mq = 0; mq < 2; ++mq)
#pragma unroll
      for (int nq = 0; nq < 2; ++nq)
#pragma unroll
        for (int n2 = 0; n2 < 2; ++n2) {
          int col = bcol + nq * 128 + wn * 32 + n2 * 16 + lq;
          int cw = col & (CC - 1);
          float bb = bias[cw] * bsc;
          int h_ = cw >> 6, d_ = cw & (HD - 1);
#pragma unroll
          for (int m4 = 0; m4 < 4; ++m4) {
            int row0 = brow + mq * 128 + wm * 64 + m4 * 16 + g * 4;
#pragma unroll
            for (int i = 0; i < 4; ++i) {
              int row = row0 + i;
              int b_ = row >> 11, t_ = row & (TT - 1);
              out[((size_t)proj << 23) +
                  ((((size_t)b_ * HH + h_) * TT + t_) << 6) + d_] =
                  (__bf16)(acc[mq][m4][nq][n2][i] + bb);
            }
          }
        }
  } else {
    // V: transpose 256x256 tile through LDS (4 chunks of 64 cols = 1 head
    // each) and write Vt[bh][d][t] coalesced. LDS main buffers are free.
    __bf16* lt = (__bf16*)&LA[0][0][0];          // [64 cols][264 rows]
    const int cv0 = (bn & 3) << 8;               // col offset within V region
    const int b_ = brow >> 11, t0 = brow & (TT - 1);
    const int hbase = (bn & 3) << 2;
    const int rd_d = tid >> 3, rd_tb = (tid & 7) << 5;
#pragma unroll
    for (int cc = 0; cc < 4; ++cc) {
      if ((wn >> 1) == (cc & 1)) {               // 4 writer waves per chunk
#pragma unroll
        for (int n2 = 0; n2 < 2; ++n2) {
          int c = ((wn & 1) << 5) + (n2 << 4) + lq;
          float bb = b2[cv0 + (cc << 6) + c];
#pragma unroll
          for (int mq = 0; mq < 2; ++mq)
#pragma unroll
            for (int m4 = 0; m4 < 4; ++m4) {
              int r = (mq << 7) + (wm << 6) + (m4 << 4) + (g << 2);
              bf16x4 pk;
#pragma unroll
              for (int i = 0; i < 4; ++i)
                pk[i] = (__bf16)(acc[mq][m4][cc >> 1][n2][i] + bb);
              *(bf16x4*)(lt + c * 264 + r) = pk;
            }
        }
      }
      __syncthreads();
      // readers: all 512 threads; d = tid>>3, 32 t-elems each
      __bf16* dst = vt + (((size_t)((b_ * HH + hbase + cc) * HD + rd_d)) << 11)
                       + t0 + rd_tb;
      const __bf16* srcl = lt + rd_d * 264 + rd_tb;
#pragma unroll
      for (int j = 0; j < 4; ++j)
        *(bf16x8*)(dst + j * 8) = *(const bf16x8*)(srcl + j * 8);
      __syncthreads();
    }
  }
}

// ---------------- proj GEMM (m97 structure): fp32 out ----------------
__global__ __launch_bounds__(256, 2)
void gemm_proj(const __bf16* __restrict__ A, const __bf16* __restrict__ Bm,
               const float* __restrict__ bias, float* __restrict__ out,
               int M, int N, int K) {
  __shared__ __bf16 As[128 * 32];
  __shared__ __bf16 Bs[128 * 32];
  const int tid = threadIdx.x;
  const int wid = tid >> 6, lane = tid & 63;
  const int g = lane >> 4, lq = lane & 15;
  const int nbn = N >> 7;
  const int brow = (blockIdx.x / nbn) << 7;
  const int bcol = (blockIdx.x % nbn) << 7;
  const int wr = (wid >> 1) << 6, wc = (wid & 1) << 6;

  f32x4 acc[4][4] = {};

  const int o0 = wid * 2048 + lane * 16;
  for (int kt = 0; kt < K; kt += 32) {
    __syncthreads();
#pragma unroll
    for (int j = 0; j < 2; ++j) {
      int o = o0 + j * 1024;
      int row = o >> 6, colb = o & 63;
      gload_lds16((const char*)A + ((size_t)(brow + row) * K + kt) * 2 + colb,
                  (char*)As + o);
      gload_lds16((const char*)Bm + ((size_t)(bcol + row) * K + kt) * 2 + colb,
                  (char*)Bs + o);
    }
    __syncthreads();
    bf16x8 av[4], bv[4];
#pragma unroll
    for (int m = 0; m < 4; ++m)
      av[m] = *(const bf16x8*)(As + (wr + m * 16 + lq) * 32 + g * 8);
#pragma unroll
    for (int n = 0; n < 4; ++n)
      bv[n] = *(const bf16x8*)(Bs + (wc + n * 16 + lq) * 32 + g * 8);
#pragma unroll
    for (int m = 0; m < 4; ++m)
#pragma unroll
      for (int n = 0; n < 4; ++n)
        acc[m][n] = __builtin_amdgcn_mfma_f32_16x16x32_bf16(av[m], bv[n], acc[m][n], 0, 0, 0);
  }

#pragma unroll
  for (int m = 0; m < 4; ++m) {
#pragma unroll
    for (int n = 0; n < 4; ++n) {
      int col = bcol + wc + n * 16 + lq;
      float bb = bias[col];
      int row0 = brow + wr + m * 16 + g * 4;
#pragma unroll
      for (int i = 0; i < 4; ++i)
        out[(size_t)(row0 + i) * N + col] = acc[m][n][i] + bb;
    }
  }
}

// ---------------- Flash attention v6 (causal + padding mask) ----------------
// grid 1024 = 16 q-tiles x 64 bh, 256 threads = 4 waves x 32 q-rows (QBLK=128).
// 32x32x16 MFMA, swapped QK^T, split-half S, in-register softmax (v5b compute
// path, harness-validated).
// v6 theory: attn was pinned ~76us across 4 structurally different versions ->
// dispatch/residency-bound, not pipe-bound (r3 counters: Occupancy 17.6%).
// Changes (residency only):
//  * DOUBLE-buffered K/V (32.8KB LDS) + launch_bounds(256,4) -> 4 blocks/CU
//    -> the ENTIRE 1024-block grid is co-resident; zero dispatch queue, no
//    FIFO tail of heavy blocks.
//  * qi map reversed (heavy-FIRST): qi = 15 - LatinSquare(jj). Residue-4
//    classes {jj, jj+4, jj+8, jj+12} each sum ntiles to 68 -> per-CU load is
//    exactly equal under round-robin block->CU assignment.
//  * pipeline: WAITV0 (own stage(t), issued one full compute phase earlier ->
//    lands free); BARR (all waves: tile t staged AND tile t-1 reads done);
//    issue stage(t+1) into buf^1 (WAR-safe by that barrier); compute(t).
//    One barrier per tile.
// C/D layout (m74/m101): col = lane&31, row = (r&3) + 8*(r>>2) + 4*(lane>>5).
__global__ __launch_bounds__(256, 4)
void attn_fwd(const __bf16* __restrict__ Q, const __bf16* __restrict__ K,
              const __bf16* __restrict__ Vt, const int* __restrict__ pm,
              __bf16* __restrict__ Y) {
  __shared__ __bf16 Ks[2][64 * 64];   // 16 KiB
  __shared__ __bf16 Vs[2][64 * 64];   // 16 KiB
  __shared__ int flg;
  const int tid = threadIdx.x, wid = tid >> 6, lane = tid & 63;
  const int l31 = lane & 31, hi = lane >> 5;
  const int bx = blockIdx.x;
  const int bh = bx & 63, jj = bx >> 6;          // jj 0..15
  // Heavy-first Latin-square qi map: qi = 15 - [4*(jj>>2) + ((jj+(jj>>2))&3)].
  // Bijective; every residue-4 class of jj sums qi to 30 (ntiles to 68) ->
  // per-CU work equal under round-robin dispatch; heaviest blocks dispatch
  // first (insurance if residency lands below 4/CU).
  const int qi = 15 - (4 * (jj >> 2) + ((jj + (jj >> 2)) & 3));
  const int b_ = bh >> 4, h_ = bh & 15;
  const __bf16* Qb = Q + (size_t)bh * TT * HD;
  const __bf16* Kb = K + (size_t)bh * TT * HD;
  const __bf16* Vb = Vt + (size_t)bh * HD * TT;
  const int* pmb = pm + b_ * TT;

  const int so = tid * 16;                 // 16B chunk, 0..4080
  const int srow = tid >> 3;               // 0..31
  const int scol = (so & 127) ^ ((srow & 7) << 4);   // inverse-swizzled src col

  const int q0 = qi << 7;
  const int qw = q0 + wid * 32;            // this wave's 32 q-rows
  const int ntiles = 2 * qi + 2;           // >= 2 always
  const int sw0 = (l31 & 7) << 4;

  // Q fragments: lane holds Q[qw+l31][16s + 8hi .. +7], s=0..3
  bf16x8 qf[4];
#pragma unroll
  for (int s = 0; s < 4; ++s)
    qf[s] = *(const bf16x8*)(Qb + (size_t)(qw + l31) * HD + s * 16 + hi * 8);
  SB0;   // pin qf loads above the staging issues (vmcnt accounting)

  // padding-mask block check: 256 threads x 2 int4 cover the 2048-int pm row
  int4 pa4 = ((const int4*)pmb)[tid];
  int4 pb4 = ((const int4*)pmb)[tid + 256];
  bool okp = pa4.x && pa4.y && pa4.z && pa4.w &&
             pb4.x && pb4.y && pb4.z && pb4.w;
  if (tid == 0) flg = 1;
  __syncthreads();
  if (!okp) flg = 0;                       // benign race (all writers store 0)

  // prologue: stage tile 0 into buf 0 (4 gloads: 2 K + 2 V)
  {
    char* kd = (char*)&Ks[0][0] + so;
    char* vd = (char*)&Vs[0][0] + so;
#pragma unroll
    for (int j = 0; j < 2; ++j) {
      gload_lds16((const char*)Kb + (size_t)(srow + 32 * j) * 128 + scol,
                  kd + j * 4096);
      gload_lds16((const char*)Vb + (size_t)(srow + 32 * j) * (TT * 2) + scol,
                  vd + j * 4096);
    }
  }
  __syncthreads();                         // tile 0 staged everywhere; flg final
  const bool allones = (flg != 0);

  f32x16 o0 = {}, o1 = {};                 // O[q=crow(r,hi)][d = l31 | 32+l31]
  f32x16 vzero = {};                       // persistent zero C-operand
  float lsum = 0.f;                        // partial row-sum (this lane-half)
  float m = -INFINITY;                     // running max for q = qw+l31

  int cur = 0;
#pragma unroll 1
  for (int t = 0; t < ntiles; ++t) {
    const int kv0 = t << 6;
    // ---- own stage(t) done (issued a full compute phase ago -> cheap) ----
    WAITV0;
    BARR; SB0;   // all waves: tile t staged AND tile t-1 reads finished
    // ---- issue stage(t+1) into buf[cur^1] (tile t-1's slot, now free) ----
    if (t + 1 < ntiles) {
      char* kd = (char*)&Ks[0][0] + (cur ^ 1) * 8192 + so;
      char* vd = (char*)&Vs[0][0] + (cur ^ 1) * 8192 + so;
      const size_t nk = (size_t)(kv0 + 64);
#pragma unroll
      for (int j = 0; j < 2; ++j) {
        gload_lds16((const char*)Kb + (nk + srow + 32 * j) * 128 + scol,
                    kd + j * 4096);
        gload_lds16((const char*)Vb + (size_t)(srow + 32 * j) * (TT * 2) +
                        nk * 2 + scol,
                    vd + j * 4096);
      }
    }

    unsigned long long bits = ~0ull;
    if (__builtin_expect(!allones, 0))     // rare slow path
      bits = __ballot(pmb[kv0 + lane] != 0);

    if (kv0 <= qw + 31) {                  // wave-uniform participation
      const char* VsC = (const char*)&Vs[0][0] + cur * 8192;

#pragma unroll
      for (int h = 0; h < 2; ++h) {
        const int kvh = kv0 + 32 * h;
        if (kvh <= qw + 31) {              // wave-uniform per-half gate
          // ---- QK^T (swapped): S[kvh+crow][q=l31] ----
          const char* KsC =
              (const char*)&Ks[0][0] + cur * 8192 + (32 * h + l31) * 128;
          f32x16 S;
          __builtin_amdgcn_s_setprio(1);
          {
            bf16x8 k0 = *(const bf16x8*)(KsC + ((16 * hi) ^ sw0));
            S = __builtin_amdgcn_mfma_f32_32x32x16_bf16(k0, qf[0], vzero, 0, 0, 0);
          }
#pragma unroll
          for (int s = 1; s < 4; ++s) {
            bf16x8 kf = *(const bf16x8*)(KsC + ((32 * s + 16 * hi) ^ sw0));
            S = __builtin_amdgcn_mfma_f32_32x32x16_bf16(kf, qf[s], S, 0, 0, 0);
          }
          __builtin_amdgcn_s_setprio(0);

          // ---- masks ----
          if (__builtin_expect(bits != ~0ull, 0)) {   // padding (rare)
#pragma unroll
            for (int r = 0; r < 16; ++r) {
              const int c = (r & 3) + 8 * (r >> 2);
              if (!((bits >> (32 * h + c + 4 * hi)) & 1ull)) S[r] = -INFINITY;
            }
          }
          if (kvh + 31 > qw) {             // causal diag (wave-uniform)
            const int thr = qw + l31 - kvh - 4 * hi;
#pragma unroll
            for (int r = 0; r < 16; ++r) {
              const int c = (r & 3) + 8 * (r >> 2);
              S[r] = (c <= thr) ? S[r] : -INFINITY;
            }
          }

          // ---- row max via packed-f32 tree + defer-rescale check ----
          f32x2 x0 = {S[0], S[1]},  x1 = {S[2], S[3]};
          f32x2 x2 = {S[4], S[5]},  x3 = {S[6], S[7]};
          f32x2 x4 = {S[8], S[9]},  x5 = {S[10], S[11]};
          f32x2 x6 = {S[12], S[13]}, x7 = {S[14], S[15]};
          x0 = max2(x0, x4); x1 = max2(x1, x5);
          x2 = max2(x2, x6); x3 = max2(x3, x7);
          x0 = max2(x0, x2); x1 = max2(x1, x3);
          x0 = max2(x0, x1);
          float pmax = fmaxf(x0[0], x0[1]);
          if (!__all(pmax <= m + 8.f)) {
            float nm = fmaxf(pmax, __shfl_xor(pmax, 32));  // full row max
            float mn = fmaxf(m, nm);
            float c = fast_exp2(m - mn);
            m = mn;
            lsum *= c;
#pragma unroll
            for (int r = 0; r < 16; ++r) {
              float cr = __shfl(c, (r & 3) + 8 * (r >> 2) + 4 * hi);
              o0[r] *= cr;
              o1[r] *= cr;
            }
          }

          // ---- P = exp2(S - m) (packed sub, trans exp) ----
          const f32x2 mm = {m, m};
#pragma unroll
          for (int r = 0; r < 16; r += 2) {
            f32x2 u = {S[r], S[r + 1]};
            u -= mm;                      // v_pk_add_f32
            S[r] = fast_exp2(u[0]);
            S[r + 1] = fast_exp2(u[1]);
          }
          // ---- in-lane row-sum via packed-f32 tree ----
          {
            f32x2 u0 = {S[0], S[1]},  u1 = {S[2], S[3]};
            f32x2 u2 = {S[4], S[5]},  u3 = {S[6], S[7]};
            f32x2 u4 = {S[8], S[9]},  u5 = {S[10], S[11]};
            f32x2 u6 = {S[12], S[13]}, u7 = {S[14], S[15]};
            u0 += u4; u1 += u5; u2 += u6; u3 += u7;
            u0 += u2; u1 += u3;
            u0 += u1;
            lsum += u0[0] + u0[1];
          }

          // ---- PV: build A-fragments (validated select+shfl_xor exchange) ----
          __builtin_amdgcn_s_setprio(1);
#pragma unroll
          for (int s = 0; s < 2; ++s) {
            int A0 = cvt_pk_bf16(S[8 * s + 0], S[8 * s + 1]);
            int A1 = cvt_pk_bf16(S[8 * s + 2], S[8 * s + 3]);
            int B0 = cvt_pk_bf16(S[8 * s + 4], S[8 * s + 5]);
            int B1 = cvt_pk_bf16(S[8 * s + 6], S[8 * s + 7]);
            // exchange across lane+-32: lo lanes need A-pairs of BOTH halves,
            // hi lanes need B-pairs of BOTH halves.
            int s0 = hi ? A0 : B0, s1 = hi ? A1 : B1;
            int e0 = __shfl_xor(s0, 32), e1 = __shfl_xor(s1, 32);
            i32x4 wv;
            wv[0] = hi ? e0 : A0;
            wv[1] = hi ? e1 : A1;
            wv[2] = hi ? B0 : e0;
            wv[3] = hi ? B1 : e1;
            bf16x8 pa = __builtin_bit_cast(bf16x8, wv);
            const int co = 64 * h + 32 * s + 16 * hi;   // kv byte offset
            bf16x8 v0 = *(const bf16x8*)(VsC + l31 * 128 + (co ^ sw0));
            bf16x8 v1 = *(const bf16x8*)(VsC + (32 + l31) * 128 + (co ^ sw0));
            o0 = __builtin_amdgcn_mfma_f32_32x32x16_bf16(pa, v0, o0, 0, 0, 0);
            o1 = __builtin_amdgcn_mfma_f32_32x32x16_bf16(pa, v1, o1, 0, 0, 0);
          }
          __builtin_amdgcn_s_setprio(0);
        }
      }
    }
    SB0;   // pin this tile's LDS reads above next iteration's barrier
    cur ^= 1;
  }

  // epilogue: combine lane-halves' row-sums, normalize + store
  float linv = 1.f / (lsum + __shfl_xor(lsum, 32));
#pragma unroll
  for (int r = 0; r < 16; ++r) {
    const int crow = (r & 3) + 8 * (r >> 2) + 4 * hi;
    float ir = __shfl(linv, crow);
    const int qrow = qw + crow;
    __bf16* yp = Y + ((size_t)(b_ * TT + qrow)) * CC + h_ * HD + l31;
    yp[0]  = (__bf16)(o0[r] * ir);
    yp[32] = (__bf16)(o1[r] * ir);
  }
}

// ---------------- launch ----------------
extern "C" void kernel_launch(void* const* d_in, const int* in_sizes, int n_in,
                              void* d_out, int out_size, void* d_ws, size_t ws_size,
                              hipStream_t stream) {
  (void)in_sizes; (void)n_in; (void)out_size; (void)ws_size;
  const float* x  = (const float*)d_in[0];
  const float* Wk = (const float*)d_in[1];
  const float* bk = (const float*)d_in[2];
  const float* Wq = (const float*)d_in[3];
  const float* bq = (const float*)d_in[4];
  const float* Wv = (const float*)d_in[5];
  const float* bv = (const float*)d_in[6];
  const float* Wp = (const float*)d_in[7];
  const float* bp = (const float*)d_in[8];
  const int* pmask = (const int*)d_in[9];

  char* ws = (char*)d_ws;
  const size_t MB = 1024 * 1024;
  __bf16* xb   = (__bf16*)(ws);            // 16MB; reused as attn-out y
  __bf16* wqkv = (__bf16*)(ws + 16 * MB);  // 6MB  [3072][1024] (q,k,v concat)
  __bf16* wpb  = (__bf16*)(ws + 22 * MB);  // 2MB
  __bf16* qb   = (__bf16*)(ws + 24 * MB);  // 16MB [B,H,T,HD]
  __bf16* kb   = qb + ((size_t)1 << 23);   // 16MB @40MB
  __bf16* vtb  = (__bf16*)(ws + 56 * MB);  // 16MB [B,H,HD,T] (written by gemm_qkv)
  __bf16* yb   = xb;                       // attn out overwrites x

  int n4 = (MM * CC) / 4;                  // 2097152
  cvt_f32_bf16<<<(n4 + 255) / 256, 256, 0, stream>>>(x, xb, n4);
  cvt_w4<<<dim3((CC * CC / 4) / 256, 4), 256, 0, stream>>>(
      Wq, Wk, Wv, Wp, wqkv, wpb);

  // fused QKV projection + V-transpose epilogue
  gemm_qkv<<<(MM / 256) * (3 * CC / 256), 512, 0, stream>>>(
      xb, wqkv, bq, bk, bv, qb, vtb);

  attn_fwd<<<NQT2 * BB * HH, 256, 0, stream>>>(qb, kb, vtb, pmask, yb);

  gemm_proj<<<(MM / 128) * (CC / 128), 256, 0, stream>>>(
      yb, wpb, bp, (float*)d_out, MM, CC, CC);
}

// Round 7
// 173.173 us; speedup vs baseline: 1.1302x; 1.0046x over previous
//
#include <hip/hip_runtime.h>
#include <hip/hip_bf16.h>
#include <math.h>
#include <stdint.h>

// Problem constants (reference: B=4, T=2048, C=1024, H=16, HD=64)
#define BB 4
#define TT 2048
#define CC 1024
#define HH 16
#define HD 64
#define MM (BB*TT)   // 8192
#define NQT2 16      // T / 128 q-tiles for attention (QBLK=128)
#define SCQ 0.180336878f   // (1/sqrt(HD)) * log2(e): Q pre-scale for exp2-domain softmax

using f32x2  = __attribute__((ext_vector_type(2))) float;
using f32x4  = __attribute__((ext_vector_type(4))) float;
using f32x16 = __attribute__((ext_vector_type(16))) float;
using i32x4  = __attribute__((ext_vector_type(4))) int;
using bf16x4 = __attribute__((ext_vector_type(4))) __bf16;
using bf16x8 = __attribute__((ext_vector_type(8))) __bf16;

__device__ __forceinline__ float fast_exp2(float x) {
  return __builtin_amdgcn_exp2f(x);   // v_exp_f32 (native exp2 on gfx950)
}

__device__ __forceinline__ int cvt_pk_bf16(float lo, float hi_) {
  int r;
  asm("v_cvt_pk_bf16_f32 %0, %1, %2" : "=v"(r) : "v"(lo), "v"(hi_));
  return r;   // low 16 = bf16(lo), high 16 = bf16(hi_)
}

__device__ __forceinline__ f32x2 max2(f32x2 a, f32x2 b) {
  return __builtin_elementwise_max(a, b);   // v_pk_max_f32
}

__device__ __forceinline__ void gload_lds16(const void* g, void* l) {
  __builtin_amdgcn_global_load_lds(
      (__attribute__((address_space(1))) void*)(void*)(g),
      (__attribute__((address_space(3))) void*)(l), 16, 0, 0);
}

// ---------------- fp32 -> bf16 converts ----------------
__global__ __launch_bounds__(256)
void cvt_f32_bf16(const float* __restrict__ s, __bf16* __restrict__ d, int n4) {
  int i = blockIdx.x * 256 + threadIdx.x;
  if (i >= n4) return;
  float4 v = ((const float4*)s)[i];
  bf16x4 o;
  o[0] = (__bf16)v.x; o[1] = (__bf16)v.y; o[2] = (__bf16)v.z; o[3] = (__bf16)v.w;
  *(bf16x4*)(d + (size_t)i * 4) = o;
}

// 4 weights in one launch; Wq scaled by SCQ and Wq/Wk/Wv written into the
// contiguous [3072][1024] concat buffer (order q,k,v); Wp separate.
__global__ __launch_bounds__(256)
void cvt_w4(const float* __restrict__ Wq, const float* __restrict__ Wk,
            const float* __restrict__ Wv, const float* __restrict__ Wp,
            __bf16* __restrict__ wqkv, __bf16* __restrict__ wpb) {
  int which = blockIdx.y;
  const float* s = which == 0 ? Wq : which == 1 ? Wk : which == 2 ? Wv : Wp;
  __bf16* d = which == 3 ? wpb : wqkv + (size_t)which * CC * CC;
  float sc = which == 0 ? SCQ : 1.f;
  int i = blockIdx.x * 256 + threadIdx.x;   // grid.x = (CC*CC/4)/256 = 1024
  float4 v = ((const float4*)s)[i];
  bf16x4 o;
  o[0] = (__bf16)(v.x * sc); o[1] = (__bf16)(v.y * sc);
  o[2] = (__bf16)(v.z * sc); o[3] = (__bf16)(v.w * sc);
  *(bf16x4*)(d + (size_t)i * 4) = o;
}

// ================== 8-phase 256x256 BK=64 QKV GEMM (m201 schedule) ==========
// C[8192,3072] = A[8192,1024] x Wqkv[3072,1024]^T + bias.
// proj 0/1 (Q,K): bf16 head-split [proj][B,H,T,HD] store.
// proj 2 (V): epilogue transposes the 256x256 tile through LDS (4 chunks of
// 64 cols) and writes Vt[bh][d][t] coalesced — replaces the transpose kernel.
// v7: XCD-chunk block swizzle (T1): grid 384 = 8 XCDs x 48; XCD x gets
// contiguous logical blocks [48x..48x+48) = 4 bm x 12 bn -> per-XCD L2
// working set = 4 A-panels (2MB) + B (6MB) instead of ~all of A+B. Targets
// the measured staging-BW wall (FETCH 79MB vs 22MB compulsory).
#define WAITV6 asm volatile("s_waitcnt vmcnt(6)" ::: "memory")
#define WAITV4 asm volatile("s_waitcnt vmcnt(4)" ::: "memory")
#define WAITV0 asm volatile("s_waitcnt vmcnt(0)" ::: "memory")
#define WAITL0 asm volatile("s_waitcnt lgkmcnt(0)" ::: "memory")
#define BARR   __builtin_amdgcn_s_barrier()
#define SB0    __builtin_amdgcn_sched_barrier(0)
#define PRIO1  __builtin_amdgcn_s_setprio(1)
#define PRIO0  __builtin_amdgcn_s_setprio(0)

#define LDA_SET(buf, mq)                                                      \
  {                                                                           \
    const char* base_ = (const char*)&LA[buf][mq][0] + (wm * 64 + lq) * 128;  \
    _Pragma("unroll")                                                         \
    for (int m4 = 0; m4 < 4; ++m4)                                            \
      _Pragma("unroll")                                                       \
      for (int kk = 0; kk < 2; ++kk)                                          \
        a[m4 * 2 + kk] =                                                      \
            *(const bf16x8*)(base_ + m4 * 2048 + ((kk * 64 + g * 16) ^ swz)); \
  }

#define LDB_SET(buf, nq)                                                      \
  {                                                                           \
    const char* base_ = (const char*)&LB[buf][nq][0] + (wn * 32 + lq) * 128;  \
    _Pragma("unroll")                                                         \
    for (int n2 = 0; n2 < 2; ++n2)                                            \
      _Pragma("unroll")                                                       \
      for (int kk = 0; kk < 2; ++kk)                                          \
        b[nq][n2 * 2 + kk] =                                                  \
            *(const bf16x8*)(base_ + n2 * 2048 + ((kk * 64 + g * 16) ^ swz)); \
  }

#define STAGE_A(nbuf, h, tt)                                                  \
  {                                                                           \
    const char* s_ = Ag + ((size_t)((h)*128 + srow)) * 2048 + (tt)*128 + scol1; \
    gload_lds16(s_, (char*)&LA[nbuf][h][0] + so16);                           \
    gload_lds16(s_ + (size_t)64 * 2048, (char*)&LA[nbuf][h][0] + so16 + 8192);\
  }

#define STAGE_B(nbuf, h, tt)                                                  \
  {                                                                           \
    const char* s_ = Bg + ((size_t)((h)*128 + srow)) * 2048 + (tt)*128 + scol1; \
    gload_lds16(s_, (char*)&LB[nbuf][h][0] + so16);                           \
    gload_lds16(s_ + (size_t)64 * 2048, (char*)&LB[nbuf][h][0] + so16 + 8192);\
  }

#define MFMA_PH(mq, nq)                                                       \
  _Pragma("unroll")                                                           \
  for (int m4 = 0; m4 < 4; ++m4)                                              \
    _Pragma("unroll")                                                         \
    for (int n2 = 0; n2 < 2; ++n2)                                            \
      _Pragma("unroll")                                                       \
      for (int kk = 0; kk < 2; ++kk)                                          \
        acc[mq][m4][nq][n2] = __builtin_amdgcn_mfma_f32_16x16x32_bf16(        \
            a[m4 * 2 + kk], b[nq][n2 * 2 + kk], acc[mq][m4][nq][n2], 0, 0, 0);

__global__ __launch_bounds__(512, 2)
void gemm_qkv(const __bf16* __restrict__ A, const __bf16* __restrict__ Bm,
              const float* __restrict__ b0, const float* __restrict__ b1,
              const float* __restrict__ b2, __bf16* __restrict__ out,
              __bf16* __restrict__ vt) {
  __shared__ __bf16 LA[2][2][128 * 64];   // [K-tile parity][half][128 x 64]
  __shared__ __bf16 LB[2][2][128 * 64];   // 128 KiB total
  const int tid = threadIdx.x, wid = tid >> 6, lane = tid & 63;
  const int g = lane >> 4, lq = lane & 15;
  const int wm = wid >> 2, wn = wid & 3;             // 2M x 4N waves
  // XCD-chunk swizzle: 384 blocks = 8 XCDs x 48 contiguous logicals (bijective)
  const int bx0 = blockIdx.x;
  const int bx = (bx0 & 7) * 48 + (bx0 >> 3);
  const int bm = bx / 12, bn = bx % 12;
  const int brow = bm << 8, bcol = bn << 8;
  const int swz = (lq & 7) << 4;

  // staging geometry: thread stages 2x16B chunks per half-tile
  const int srow = tid >> 3, so16 = tid * 16;
  const int scol1 = ((tid & 7) << 4) ^ ((srow & 7) << 4);  // inverse-swizzled src col
  const char* Ag = (const char*)A + (size_t)brow * 2048;   // K=1024 -> 2048B rows
  const char* Bg = (const char*)Bm + (size_t)bcol * 2048;

  f32x4 acc[2][4][2][2] = {};
  bf16x8 a[8], b[2][4];

  // prologue: 7 halves = tile0 {A0,B0,B1,A1} + tile1 {A0,B0,B1}
  STAGE_A(0, 0, 0); STAGE_B(0, 0, 0); STAGE_B(0, 1, 0); STAGE_A(0, 1, 0);
  STAGE_A(1, 0, 1); STAGE_B(1, 0, 1); STAGE_B(1, 1, 1);
  WAITV6; BARR;

#pragma unroll 1
  for (int t = 0; t < 8; ++t) {
    const bool s2 = (t < 7);
    const int k1 = 2 * t + 1, k2 = 2 * t + 2, k3 = 2 * t + 3;
    // ---- p1: tile 2t (buf0) quad (0,0); stage A1(2t+1) ----
    LDA_SET(0, 0); LDB_SET(0, 0);
    STAGE_A(1, 1, k1);
    BARR; WAITL0; SB0;
    PRIO1; MFMA_PH(0, 0); PRIO0; BARR;
    // ---- p2: quad (0,1); stage A0(2t+2) ----
    LDB_SET(0, 1);
    if (s2) STAGE_A(0, 0, k2);
    BARR; WAITL0; SB0;
    PRIO1; MFMA_PH(0, 1); PRIO0; BARR;
    // ---- p3: quad (1,1); stage B0(2t+2) ----
    LDA_SET(0, 1);
    if (s2) STAGE_B(0, 0, k2);
    BARR; WAITL0; SB0;
    PRIO1; MFMA_PH(1, 1); PRIO0; BARR;
    // ---- p4: quad (1,0); stage B1(2t+2); counted vmcnt ----
    if (s2) { STAGE_B(0, 1, k2); WAITV6; } else { WAITV0; }
    BARR; SB0;
    PRIO1; MFMA_PH(1, 0); PRIO0; BARR;
    // ---- p5: tile 2t+1 (buf1) quad (0,0); stage A1(2t+2) ----
    LDA_SET(1, 0); LDB_SET(1, 0);
    if (s2) STAGE_A(0, 1, k2);
    BARR; WAITL0; SB0;
    PRIO1; MFMA_PH(0, 0); PRIO0; BARR;
    // ---- p6: quad (0,1); stage A0(2t+3) ----
    LDB_SET(1, 1);
    if (s2) STAGE_A(1, 0, k3);
    BARR; WAITL0; SB0;
    PRIO1; MFMA_PH(0, 1); PRIO0; BARR;
    // ---- p7: quad (1,1); stage B0(2t+3) ----
    LDA_SET(1, 1);
    if (s2) STAGE_B(1, 0, k3);
    BARR; WAITL0; SB0;
    PRIO1; MFMA_PH(1, 1); PRIO0; BARR;
    // ---- p8: quad (1,0); stage B1(2t+3); counted vmcnt ----
    if (s2) { STAGE_B(1, 1, k3); WAITV6; }
    BARR; SB0;
    PRIO1; MFMA_PH(1, 0); PRIO0; BARR;
  }

  const int proj = bn >> 2;   // uniform per block (256 | 1024)
  if (proj < 2) {
    // epilogue: bias + bf16 head-split store [proj][B,H,T,HD]
    const float* bias = proj == 0 ? b0 : b1;
    const float bsc = proj == 0 ? SCQ : 1.f;
#pragma unroll
    for (int mq = 0; mq < 2; ++mq)
#pragma unroll
      for (int nq = 0; nq < 2; ++nq)
#pragma unroll
        for (int n2 = 0; n2 < 2; ++n2) {
          int col = bcol + nq * 128 + wn * 32 + n2 * 16 + lq;
          int cw = col & (CC - 1);
          float bb = bias[cw] * bsc;
          int h_ = cw >> 6, d_ = cw & (HD - 1);
#pragma unroll
          for (int m4 = 0; m4 < 4; ++m4) {
            int row0 = brow + mq * 128 + wm * 64 + m4 * 16 + g * 4;
#pragma unroll
            for (int i = 0; i < 4; ++i) {
              int row = row0 + i;
              int b_ = row >> 11, t_ = row & (TT - 1);
              out[((size_t)proj << 23) +
                  ((((size_t)b_ * HH + h_) * TT + t_) << 6) + d_] =
                  (__bf16)(acc[mq][m4][nq][n2][i] + bb);
            }
          }
        }
  } else {
    // V: transpose 256x256 tile through LDS (4 chunks of 64 cols = 1 head
    // each) and write Vt[bh][d][t] coalesced. LDS main buffers are free.
    __bf16* lt = (__bf16*)&LA[0][0][0];          // [64 cols][264 rows]
    const int cv0 = (bn & 3) << 8;               // col offset within V region
    const int b_ = brow >> 11, t0 = brow & (TT - 1);
    const int hbase = (bn & 3) << 2;
    const int rd_d = tid >> 3, rd_tb = (tid & 7) << 5;
#pragma unroll
    for (int cc = 0; cc < 4; ++cc) {
      if ((wn >> 1) == (cc & 1)) {               // 4 writer waves per chunk
#pragma unroll
        for (int n2 = 0; n2 < 2; ++n2) {
          int c = ((wn & 1) << 5) + (n2 << 4) + lq;
          float bb = b2[cv0 + (cc << 6) + c];
#pragma unroll
          for (int mq = 0; mq < 2; ++mq)
#pragma unroll
            for (int m4 = 0; m4 < 4; ++m4) {
              int r = (mq << 7) + (wm << 6) + (m4 << 4) + (g << 2);
              bf16x4 pk;
#pragma unroll
              for (int i = 0; i < 4; ++i)
                pk[i] = (__bf16)(acc[mq][m4][cc >> 1][n2][i] + bb);
              *(bf16x4*)(lt + c * 264 + r) = pk;
            }
        }
      }
      __syncthreads();
      // readers: all 512 threads; d = tid>>3, 32 t-elems each
      __bf16* dst = vt + (((size_t)((b_ * HH + hbase + cc) * HD + rd_d)) << 11)
                       + t0 + rd_tb;
      const __bf16* srcl = lt + rd_d * 264 + rd_tb;
#pragma unroll
      for (int j = 0; j < 4; ++j)
        *(bf16x8*)(dst + j * 8) = *(const bf16x8*)(srcl + j * 8);
      __syncthreads();
    }
  }
}

// ---------------- proj GEMM (m97 structure): fp32 out ----------------
__global__ __launch_bounds__(256, 2)
void gemm_proj(const __bf16* __restrict__ A, const __bf16* __restrict__ Bm,
               const float* __restrict__ bias, float* __restrict__ out,
               int M, int N, int K) {
  __shared__ __bf16 As[128 * 32];
  __shared__ __bf16 Bs[128 * 32];
  const int tid = threadIdx.x;
  const int wid = tid >> 6, lane = tid & 63;
  const int g = lane >> 4, lq = lane & 15;
  const int nbn = N >> 7;
  // XCD-chunk swizzle (bijective when gridDim.x % 8 == 0; our launch: 512)
  int bx = blockIdx.x;
  const int nb = gridDim.x;
  if ((nb & 7) == 0) { const int q = nb >> 3; bx = (bx & 7) * q + (bx >> 3); }
  const int brow = (bx / nbn) << 7;
  const int bcol = (bx % nbn) << 7;
  const int wr = (wid >> 1) << 6, wc = (wid & 1) << 6;

  f32x4 acc[4][4] = {};

  const int o0 = wid * 2048 + lane * 16;
  for (int kt = 0; kt < K; kt += 32) {
    __syncthreads();
#pragma unroll
    for (int j = 0; j < 2; ++j) {
      int o = o0 + j * 1024;
      int row = o >> 6, colb = o & 63;
      gload_lds16((const char*)A + ((size_t)(brow + row) * K + kt) * 2 + colb,
                  (char*)As + o);
      gload_lds16((const char*)Bm + ((size_t)(bcol + row) * K + kt) * 2 + colb,
                  (char*)Bs + o);
    }
    __syncthreads();
    bf16x8 av[4], bv[4];
#pragma unroll
    for (int m = 0; m < 4; ++m)
      av[m] = *(const bf16x8*)(As + (wr + m * 16 + lq) * 32 + g * 8);
#pragma unroll
    for (int n = 0; n < 4; ++n)
      bv[n] = *(const bf16x8*)(Bs + (wc + n * 16 + lq) * 32 + g * 8);
#pragma unroll
    for (int m = 0; m < 4; ++m)
#pragma unroll
      for (int n = 0; n < 4; ++n)
        acc[m][n] = __builtin_amdgcn_mfma_f32_16x16x32_bf16(av[m], bv[n], acc[m][n], 0, 0, 0);
  }

#pragma unroll
  for (int m = 0; m < 4; ++m) {
#pragma unroll
    for (int n = 0; n < 4; ++n) {
      int col = bcol + wc + n * 16 + lq;
      float bb = bias[col];
      int row0 = brow + wr + m * 16 + g * 4;
#pragma unroll
      for (int i = 0; i < 4; ++i)
        out[(size_t)(row0 + i) * N + col] = acc[m][n][i] + bb;
    }
  }
}

// ---------------- Flash attention v6 (causal + padding mask) ----------------
// grid 1024 = 16 q-tiles x 64 bh, 256 threads = 4 waves x 32 q-rows (QBLK=128).
// 32x32x16 MFMA, swapped QK^T, split-half S, in-register softmax.
// Full-grid residency: double-buffered K/V (32.8KB LDS) + launch_bounds(256,4)
// -> 4 blocks/CU -> all 1024 blocks co-resident. Heavy-first Latin-square qi
// map balances per-CU work. One barrier per tile, counted staging.
// NOTE: attn blocks with the same bh already share an XCD (bx%8 == bh%8), so
// K/V L2 locality is already optimal — no swizzle needed here.
// C/D layout (m74/m101): col = lane&31, row = (r&3) + 8*(r>>2) + 4*(lane>>5).
__global__ __launch_bounds__(256, 4)
void attn_fwd(const __bf16* __restrict__ Q, const __bf16* __restrict__ K,
              const __bf16* __restrict__ Vt, const int* __restrict__ pm,
              __bf16* __restrict__ Y) {
  __shared__ __bf16 Ks[2][64 * 64];   // 16 KiB
  __shared__ __bf16 Vs[2][64 * 64];   // 16 KiB
  __shared__ int flg;
  const int tid = threadIdx.x, wid = tid >> 6, lane = tid & 63;
  const int l31 = lane & 31, hi = lane >> 5;
  const int bx = blockIdx.x;
  const int bh = bx & 63, jj = bx >> 6;          // jj 0..15
  const int qi = 15 - (4 * (jj >> 2) + ((jj + (jj >> 2)) & 3));
  const int b_ = bh >> 4, h_ = bh & 15;
  const __bf16* Qb = Q + (size_t)bh * TT * HD;
  const __bf16* Kb = K + (size_t)bh * TT * HD;
  const __bf16* Vb = Vt + (size_t)bh * HD * TT;
  const int* pmb = pm + b_ * TT;

  const int so = tid * 16;                 // 16B chunk, 0..4080
  const int srow = tid >> 3;               // 0..31
  const int scol = (so & 127) ^ ((srow & 7) << 4);   // inverse-swizzled src col

  const int q0 = qi << 7;
  const int qw = q0 + wid * 32;            // this wave's 32 q-rows
  const int ntiles = 2 * qi + 2;           // >= 2 always
  const int sw0 = (l31 & 7) << 4;

  // Q fragments: lane holds Q[qw+l31][16s + 8hi .. +7], s=0..3
  bf16x8 qf[4];
#pragma unroll
  for (int s = 0; s < 4; ++s)
    qf[s] = *(const bf16x8*)(Qb + (size_t)(qw + l31) * HD + s * 16 + hi * 8);
  SB0;   // pin qf loads above the staging issues (vmcnt accounting)

  // padding-mask block check: 256 threads x 2 int4 cover the 2048-int pm row
  int4 pa4 = ((const int4*)pmb)[tid];
  int4 pb4 = ((const int4*)pmb)[tid + 256];
  bool okp = pa4.x && pa4.y && pa4.z && pa4.w &&
             pb4.x && pb4.y && pb4.z && pb4.w;
  if (tid == 0) flg = 1;
  __syncthreads();
  if (!okp) flg = 0;                       // benign race (all writers store 0)

  // prologue: stage tile 0 into buf 0 (4 gloads: 2 K + 2 V)
  {
    char* kd = (char*)&Ks[0][0] + so;
    char* vd = (char*)&Vs[0][0] + so;
#pragma unroll
    for (int j = 0; j < 2; ++j) {
      gload_lds16((const char*)Kb + (size_t)(srow + 32 * j) * 128 + scol,
                  kd + j * 4096);
      gload_lds16((const char*)Vb + (size_t)(srow + 32 * j) * (TT * 2) + scol,
                  vd + j * 4096);
    }
  }
  __syncthreads();                         // tile 0 staged everywhere; flg final
  const bool allones = (flg != 0);

  f32x16 o0 = {}, o1 = {};                 // O[q=crow(r,hi)][d = l31 | 32+l31]
  f32x16 vzero = {};                       // persistent zero C-operand
  float lsum = 0.f;                        // partial row-sum (this lane-half)
  float m = -INFINITY;                     // running max for q = qw+l31

  int cur = 0;
#pragma unroll 1
  for (int t = 0; t < ntiles; ++t) {
    const int kv0 = t << 6;
    // ---- own stage(t) done (issued a full compute phase ago -> cheap) ----
    WAITV0;
    BARR; SB0;   // all waves: tile t staged AND tile t-1 reads finished
    // ---- issue stage(t+1) into buf[cur^1] (tile t-1's slot, now free) ----
    if (t + 1 < ntiles) {
      char* kd = (char*)&Ks[0][0] + (cur ^ 1) * 8192 + so;
      char* vd = (char*)&Vs[0][0] + (cur ^ 1) * 8192 + so;
      const size_t nk = (size_t)(kv0 + 64);
#pragma unroll
      for (int j = 0; j < 2; ++j) {
        gload_lds16((const char*)Kb + (nk + srow + 32 * j) * 128 + scol,
                    kd + j * 4096);
        gload_lds16((const char*)Vb + (size_t)(srow + 32 * j) * (TT * 2) +
                        nk * 2 + scol,
                    vd + j * 4096);
      }
    }

    unsigned long long bits = ~0ull;
    if (__builtin_expect(!allones, 0))     // rare slow path
      bits = __ballot(pmb[kv0 + lane] != 0);

    if (kv0 <= qw + 31) {                  // wave-uniform participation
      const char* VsC = (const char*)&Vs[0][0] + cur * 8192;

#pragma unroll
      for (int h = 0; h < 2; ++h) {
        const int kvh = kv0 + 32 * h;
        if (kvh <= qw + 31) {              // wave-uniform per-half gate
          // ---- QK^T (swapped): S[kvh+crow][q=l31] ----
          const char* KsC =
              (const char*)&Ks[0][0] + cur * 8192 + (32 * h + l31) * 128;
          f32x16 S;
          __builtin_amdgcn_s_setprio(1);
          {
            bf16x8 k0 = *(const bf16x8*)(KsC + ((16 * hi) ^ sw0));
            S = __builtin_amdgcn_mfma_f32_32x32x16_bf16(k0, qf[0], vzero, 0, 0, 0);
          }
#pragma unroll
          for (int s = 1; s < 4; ++s) {
            bf16x8 kf = *(const bf16x8*)(KsC + ((32 * s + 16 * hi) ^ sw0));
            S = __builtin_amdgcn_mfma_f32_32x32x16_bf16(kf, qf[s], S, 0, 0, 0);
          }
          __builtin_amdgcn_s_setprio(0);

          // ---- masks ----
          if (__builtin_expect(bits != ~0ull, 0)) {   // padding (rare)
#pragma unroll
            for (int r = 0; r < 16; ++r) {
              const int c = (r & 3) + 8 * (r >> 2);
              if (!((bits >> (32 * h + c + 4 * hi)) & 1ull)) S[r] = -INFINITY;
            }
          }
          if (kvh + 31 > qw) {             // causal diag (wave-uniform)
            const int thr = qw + l31 - kvh - 4 * hi;
#pragma unroll
            for (int r = 0; r < 16; ++r) {
              const int c = (r & 3) + 8 * (r >> 2);
              S[r] = (c <= thr) ? S[r] : -INFINITY;
            }
          }

          // ---- row max via packed-f32 tree + defer-rescale check ----
          f32x2 x0 = {S[0], S[1]},  x1 = {S[2], S[3]};
          f32x2 x2 = {S[4], S[5]},  x3 = {S[6], S[7]};
          f32x2 x4 = {S[8], S[9]},  x5 = {S[10], S[11]};
          f32x2 x6 = {S[12], S[13]}, x7 = {S[14], S[15]};
          x0 = max2(x0, x4); x1 = max2(x1, x5);
          x2 = max2(x2, x6); x3 = max2(x3, x7);
          x0 = max2(x0, x2); x1 = max2(x1, x3);
          x0 = max2(x0, x1);
          float pmax = fmaxf(x0[0], x0[1]);
          if (!__all(pmax <= m + 8.f)) {
            float nm = fmaxf(pmax, __shfl_xor(pmax, 32));  // full row max
            float mn = fmaxf(m, nm);
            float c = fast_exp2(m - mn);
            m = mn;
            lsum *= c;
#pragma unroll
            for (int r = 0; r < 16; ++r) {
              float cr = __shfl(c, (r & 3) + 8 * (r >> 2) + 4 * hi);
              o0[r] *= cr;
              o1[r] *= cr;
            }
          }

          // ---- P = exp2(S - m) (packed sub, trans exp) ----
          const f32x2 mm = {m, m};
#pragma unroll
          for (int r = 0; r < 16; r += 2) {
            f32x2 u = {S[r], S[r + 1]};
            u -= mm;                      // v_pk_add_f32
            S[r] = fast_exp2(u[0]);
            S[r + 1] = fast_exp2(u[1]);
          }
          // ---- in-lane row-sum via packed-f32 tree ----
          {
            f32x2 u0 = {S[0], S[1]},  u1 = {S[2], S[3]};
            f32x2 u2 = {S[4], S[5]},  u3 = {S[6], S[7]};
            f32x2 u4 = {S[8], S[9]},  u5 = {S[10], S[11]};
            f32x2 u6 = {S[12], S[13]}, u7 = {S[14], S[15]};
            u0 += u4; u1 += u5; u2 += u6; u3 += u7;
            u0 += u2; u1 += u3;
            u0 += u1;
            lsum += u0[0] + u0[1];
          }

          // ---- PV: build A-fragments (validated select+shfl_xor exchange) ----
          __builtin_amdgcn_s_setprio(1);
#pragma unroll
          for (int s = 0; s < 2; ++s) {
            int A0 = cvt_pk_bf16(S[8 * s + 0], S[8 * s + 1]);
            int A1 = cvt_pk_bf16(S[8 * s + 2], S[8 * s + 3]);
            int B0 = cvt_pk_bf16(S[8 * s + 4], S[8 * s + 5]);
            int B1 = cvt_pk_bf16(S[8 * s + 6], S[8 * s + 7]);
            // exchange across lane+-32: lo lanes need A-pairs of BOTH halves,
            // hi lanes need B-pairs of BOTH halves.
            int s0 = hi ? A0 : B0, s1 = hi ? A1 : B1;
            int e0 = __shfl_xor(s0, 32), e1 = __shfl_xor(s1, 32);
            i32x4 wv;
            wv[0] = hi ? e0 : A0;
            wv[1] = hi ? e1 : A1;
            wv[2] = hi ? B0 : e0;
            wv[3] = hi ? B1 : e1;
            bf16x8 pa = __builtin_bit_cast(bf16x8, wv);
            const int co = 64 * h + 32 * s + 16 * hi;   // kv byte offset
            bf16x8 v0 = *(const bf16x8*)(VsC + l31 * 128 + (co ^ sw0));
            bf16x8 v1 = *(const bf16x8*)(VsC + (32 + l31) * 128 + (co ^ sw0));
            o0 = __builtin_amdgcn_mfma_f32_32x32x16_bf16(pa, v0, o0, 0, 0, 0);
            o1 = __builtin_amdgcn_mfma_f32_32x32x16_bf16(pa, v1, o1, 0, 0, 0);
          }
          __builtin_amdgcn_s_setprio(0);
        }
      }
    }
    SB0;   // pin this tile's LDS reads above next iteration's barrier
    cur ^= 1;
  }

  // epilogue: combine lane-halves' row-sums, normalize + store
  float linv = 1.f / (lsum + __shfl_xor(lsum, 32));
#pragma unroll
  for (int r = 0; r < 16; ++r) {
    const int crow = (r & 3) + 8 * (r >> 2) + 4 * hi;
    float ir = __shfl(linv, crow);
    const int qrow = qw + crow;
    __bf16* yp = Y + ((size_t)(b_ * TT + qrow)) * CC + h_ * HD + l31;
    yp[0]  = (__bf16)(o0[r] * ir);
    yp[32] = (__bf16)(o1[r] * ir);
  }
}

// ---------------- launch ----------------
extern "C" void kernel_launch(void* const* d_in, const int* in_sizes, int n_in,
                              void* d_out, int out_size, void* d_ws, size_t ws_size,
                              hipStream_t stream) {
  (void)in_sizes; (void)n_in; (void)out_size; (void)ws_size;
  const float* x  = (const float*)d_in[0];
  const float* Wk = (const float*)d_in[1];
  const float* bk = (const float*)d_in[2];
  const float* Wq = (const float*)d_in[3];
  const float* bq = (const float*)d_in[4];
  const float* Wv = (const float*)d_in[5];
  const float* bv = (const float*)d_in[6];
  const float* Wp = (const float*)d_in[7];
  const float* bp = (const float*)d_in[8];
  const int* pmask = (const int*)d_in[9];

  char* ws = (char*)d_ws;
  const size_t MB = 1024 * 1024;
  __bf16* xb   = (__bf16*)(ws);            // 16MB; reused as attn-out y
  __bf16* wqkv = (__bf16*)(ws + 16 * MB);  // 6MB  [3072][1024] (q,k,v concat)
  __bf16* wpb  = (__bf16*)(ws + 22 * MB);  // 2MB
  __bf16* qb   = (__bf16*)(ws + 24 * MB);  // 16MB [B,H,T,HD]
  __bf16* kb   = qb + ((size_t)1 << 23);   // 16MB @40MB
  __bf16* vtb  = (__bf16*)(ws + 56 * MB);  // 16MB [B,H,HD,T] (written by gemm_qkv)
  __bf16* yb   = xb;                       // attn out overwrites x

  int n4 = (MM * CC) / 4;                  // 2097152
  cvt_f32_bf16<<<(n4 + 255) / 256, 256, 0, stream>>>(x, xb, n4);
  cvt_w4<<<dim3((CC * CC / 4) / 256, 4), 256, 0, stream>>>(
      Wq, Wk, Wv, Wp, wqkv, wpb);

  // fused QKV projection + V-transpose epilogue
  gemm_qkv<<<(MM / 256) * (3 * CC / 256), 512, 0, stream>>>(
      xb, wqkv, bq, bk, bv, qb, vtb);

  attn_fwd<<<NQT2 * BB * HH, 256, 0, stream>>>(qb, kb, vtb, pmask, yb);

  gemm_proj<<<(MM / 128) * (CC / 128), 256, 0, stream>>>(
      yb, wpb, bp, (float*)d_out, MM, CC, CC);
}

// Round 8
// 173.142 us; speedup vs baseline: 1.1304x; 1.0002x over previous
//
#include <hip/hip_runtime.h>
#include <hip/hip_bf16.h>
#include <math.h>
#include <stdint.h>

// Problem constants (reference: B=4, T=2048, C=1024, H=16, HD=64)
#define BB 4
#define TT 2048
#define CC 1024
#define HH 16
#define HD 64
#define MM (BB*TT)   // 8192
#define NQT2 16      // T / 128 q-tiles for attention (QBLK=128)
#define SCQ 0.180336878f   // (1/sqrt(HD)) * log2(e): Q pre-scale for exp2-domain softmax

using f32x2  = __attribute__((ext_vector_type(2))) float;
using f32x4  = __attribute__((ext_vector_type(4))) float;
using f32x16 = __attribute__((ext_vector_type(16))) float;
using i32x4  = __attribute__((ext_vector_type(4))) int;
using bf16x4 = __attribute__((ext_vector_type(4))) __bf16;
using bf16x8 = __attribute__((ext_vector_type(8))) __bf16;

__device__ __forceinline__ float fast_exp2(float x) {
  return __builtin_amdgcn_exp2f(x);   // v_exp_f32 (native exp2 on gfx950)
}

__device__ __forceinline__ int cvt_pk_bf16(float lo, float hi_) {
  int r;
  asm("v_cvt_pk_bf16_f32 %0, %1, %2" : "=v"(r) : "v"(lo), "v"(hi_));
  return r;   // low 16 = bf16(lo), high 16 = bf16(hi_)
}

__device__ __forceinline__ f32x2 max2(f32x2 a, f32x2 b) {
  return __builtin_elementwise_max(a, b);   // v_pk_max_f32
}

__device__ __forceinline__ void gload_lds16(const void* g, void* l) {
  __builtin_amdgcn_global_load_lds(
      (__attribute__((address_space(1))) void*)(void*)(g),
      (__attribute__((address_space(3))) void*)(l), 16, 0, 0);
}

// ---------------- fp32 -> bf16 converts ----------------
__global__ __launch_bounds__(256)
void cvt_f32_bf16(const float* __restrict__ s, __bf16* __restrict__ d, int n4) {
  int i = blockIdx.x * 256 + threadIdx.x;
  if (i >= n4) return;
  float4 v = ((const float4*)s)[i];
  bf16x4 o;
  o[0] = (__bf16)v.x; o[1] = (__bf16)v.y; o[2] = (__bf16)v.z; o[3] = (__bf16)v.w;
  *(bf16x4*)(d + (size_t)i * 4) = o;
}

// 4 weights in one launch; Wq scaled by SCQ and Wq/Wk/Wv written into the
// contiguous [3072][1024] concat buffer (order q,k,v); Wp separate.
__global__ __launch_bounds__(256)
void cvt_w4(const float* __restrict__ Wq, const float* __restrict__ Wk,
            const float* __restrict__ Wv, const float* __restrict__ Wp,
            __bf16* __restrict__ wqkv, __bf16* __restrict__ wpb) {
  int which = blockIdx.y;
  const float* s = which == 0 ? Wq : which == 1 ? Wk : which == 2 ? Wv : Wp;
  __bf16* d = which == 3 ? wpb : wqkv + (size_t)which * CC * CC;
  float sc = which == 0 ? SCQ : 1.f;
  int i = blockIdx.x * 256 + threadIdx.x;   // grid.x = (CC*CC/4)/256 = 1024
  float4 v = ((const float4*)s)[i];
  bf16x4 o;
  o[0] = (__bf16)(v.x * sc); o[1] = (__bf16)(v.y * sc);
  o[2] = (__bf16)(v.z * sc); o[3] = (__bf16)(v.w * sc);
  *(bf16x4*)(d + (size_t)i * 4) = o;
}

// ============ 4-phase 256x128 BK=64 QKV GEMM (m201-derived ledger) ==========
// C[8192,3072] = A[8192,1024] x Wqkv[3072,1024]^T + bias.
// v8: tile 256x128 -> grid 32x24 = 768 = EXACTLY 3 dispatch rounds of 256
// (the 256x256 tile gave 384 blocks = 2 rounds with half the chip idle in
// round 2 — the measured wall). LDS 96KB (LA 64 + LB 32), 8 waves (2Mx4N),
// per-wave output 128x32, 16 MFMA per phase (same granularity as m201).
// Ledger: invariant 4 gloads outstanding entering each iter (next tile's
// A0+B); p2/p4 top up and WAITV4 certifies the tile about to be computed.
// XCD-chunk swizzle: 768 = 8 XCDs x 96 contiguous logicals.
// proj 0/1 (Q,K): bf16 head-split store; proj 2 (V): 2x 64-col LDS transpose
// chunks -> Vt[bh][d][t].
#define WAITV4 asm volatile("s_waitcnt vmcnt(4)" ::: "memory")
#define WAITV0 asm volatile("s_waitcnt vmcnt(0)" ::: "memory")
#define WAITL0 asm volatile("s_waitcnt lgkmcnt(0)" ::: "memory")
#define BARR   __builtin_amdgcn_s_barrier()
#define SB0    __builtin_amdgcn_sched_barrier(0)
#define PRIO1  __builtin_amdgcn_s_setprio(1)
#define PRIO0  __builtin_amdgcn_s_setprio(0)

#define LDA_SET(buf, mq)                                                      \
  {                                                                           \
    const char* base_ = (const char*)&LA[buf][mq][0] + (wm * 64 + lq) * 128;  \
    _Pragma("unroll")                                                         \
    for (int m4 = 0; m4 < 4; ++m4)                                            \
      _Pragma("unroll")                                                       \
      for (int kk = 0; kk < 2; ++kk)                                          \
        a[m4 * 2 + kk] =                                                      \
            *(const bf16x8*)(base_ + m4 * 2048 + ((kk * 64 + g * 16) ^ swz)); \
  }

#define LDB_SET(buf)                                                          \
  {                                                                           \
    const char* base_ = (const char*)&LB[buf][0] + (wn * 32 + lq) * 128;      \
    _Pragma("unroll")                                                         \
    for (int n2 = 0; n2 < 2; ++n2)                                            \
      _Pragma("unroll")                                                       \
      for (int kk = 0; kk < 2; ++kk)                                          \
        b[n2 * 2 + kk] =                                                      \
            *(const bf16x8*)(base_ + n2 * 2048 + ((kk * 64 + g * 16) ^ swz)); \
  }

#define STAGE_A(nbuf, h, tt)                                                  \
  {                                                                           \
    const char* s_ = Ag + ((size_t)((h)*128 + srow)) * 2048 + (tt)*128 + scol1; \
    gload_lds16(s_, (char*)&LA[nbuf][h][0] + so16);                           \
    gload_lds16(s_ + (size_t)64 * 2048, (char*)&LA[nbuf][h][0] + so16 + 8192);\
  }

#define STAGE_B(nbuf, tt)                                                     \
  {                                                                           \
    const char* s_ = Bg + (size_t)srow * 2048 + (tt)*128 + scol1;             \
    gload_lds16(s_, (char*)&LB[nbuf][0] + so16);                              \
    gload_lds16(s_ + (size_t)64 * 2048, (char*)&LB[nbuf][0] + so16 + 8192);   \
  }

#define MFMA_PH(mq)                                                           \
  _Pragma("unroll")                                                           \
  for (int m4 = 0; m4 < 4; ++m4)                                              \
    _Pragma("unroll")                                                         \
    for (int n2 = 0; n2 < 2; ++n2)                                            \
      _Pragma("unroll")                                                       \
      for (int kk = 0; kk < 2; ++kk)                                          \
        acc[mq][m4][n2] = __builtin_amdgcn_mfma_f32_16x16x32_bf16(            \
            a[m4 * 2 + kk], b[n2 * 2 + kk], acc[mq][m4][n2], 0, 0, 0);

__global__ __launch_bounds__(512, 2)
void gemm_qkv(const __bf16* __restrict__ A, const __bf16* __restrict__ Bm,
              const float* __restrict__ b0, const float* __restrict__ b1,
              const float* __restrict__ b2, __bf16* __restrict__ out,
              __bf16* __restrict__ vt) {
  __shared__ __bf16 LA[2][2][128 * 64];   // [K-parity][M-half][128 x 64] 64KB
  __shared__ __bf16 LB[2][128 * 64];      // [K-parity][128 x 64]         32KB
  const int tid = threadIdx.x, wid = tid >> 6, lane = tid & 63;
  const int g = lane >> 4, lq = lane & 15;
  const int wm = wid >> 2, wn = wid & 3;             // 2M x 4N waves
  // XCD-chunk swizzle: 768 blocks = 8 XCDs x 96 contiguous logicals
  const int bx0 = blockIdx.x;
  const int bx = (bx0 & 7) * 96 + (bx0 >> 3);
  const int bm = bx / 24, bn = bx % 24;
  const int brow = bm << 8, bcol = bn << 7;
  const int swz = (lq & 7) << 4;

  // staging geometry: each stage unit = 2x16B chunks/thread = 128x64 bf16
  const int srow = tid >> 3, so16 = tid * 16;
  const int scol1 = ((tid & 7) << 4) ^ ((srow & 7) << 4);  // inverse-swizzled src col
  const char* Ag = (const char*)A + (size_t)brow * 2048;   // K=1024 -> 2048B rows
  const char* Bg = (const char*)Bm + (size_t)bcol * 2048;

  f32x4 acc[2][4][2] = {};
  bf16x8 a[8], b[4];

  // prologue: k0 full {A0,A1,B} + k1 partial {A0,B}  (10 gloads)
  STAGE_A(0, 0, 0); STAGE_A(0, 1, 0); STAGE_B(0, 0);
  STAGE_A(1, 0, 1); STAGE_B(1, 1);
  WAITV4; BARR;    // k0 landed; k1's {A0,B} (4) in flight

#pragma unroll 1
  for (int t = 0; t < 8; ++t) {
    const bool s2 = (t < 7);
    const int k1 = 2 * t + 1, k2 = 2 * t + 2, k3 = 2 * t + 3;
    // ---- p1: K-tile 2t (buf0), M-half 0; stage A1(k1) ----
    LDA_SET(0, 0); LDB_SET(0);
    STAGE_A(1, 1, k1);                       // O: 4 -> 6
    BARR; WAITL0; SB0;
    PRIO1; MFMA_PH(0); PRIO0; BARR;
    // ---- p2: M-half 1; stage A0(k2)+B(k2); certify k1 ----
    LDA_SET(0, 1);
    if (s2) { STAGE_A(0, 0, k2); STAGE_B(0, k2); WAITV4; }  // O: 10 -> 4
    else    { WAITV0; }
    BARR; WAITL0; SB0;
    PRIO1; MFMA_PH(1); PRIO0; BARR;
    // ---- p3: K-tile 2t+1 (buf1), M-half 0; stage A1(k2) ----
    LDA_SET(1, 0); LDB_SET(1);
    if (s2) STAGE_A(0, 1, k2);               // O: 4 -> 6
    BARR; WAITL0; SB0;
    PRIO1; MFMA_PH(0); PRIO0; BARR;
    // ---- p4: M-half 1; stage A0(k3)+B(k3); certify k2 ----
    LDA_SET(1, 1);
    if (s2) { STAGE_A(1, 0, k3); STAGE_B(1, k3); WAITV4; }  // O: 10 -> 4
    BARR; WAITL0; SB0;
    PRIO1; MFMA_PH(1); PRIO0; BARR;
  }

  const int proj = bn >> 3;   // uniform per block (8x128 = 1024 cols / proj)
  if (proj < 2) {
    // epilogue: bias + bf16 head-split store [proj][B,H,T,HD]
    const float* bias = proj == 0 ? b0 : b1;
    const float bsc = proj == 0 ? SCQ : 1.f;
#pragma unroll
    for (int mq = 0; mq < 2; ++mq)
#pragma unroll
      for (int n2 = 0; n2 < 2; ++n2) {
        int col = bcol + wn * 32 + n2 * 16 + lq;
        int cw = col & (CC - 1);
        float bb = bias[cw] * bsc;
        int h_ = cw >> 6, d_ = cw & (HD - 1);
#pragma unroll
        for (int m4 = 0; m4 < 4; ++m4) {
          int row0 = brow + mq * 128 + wm * 64 + m4 * 16 + g * 4;
#pragma unroll
          for (int i = 0; i < 4; ++i) {
            int row = row0 + i;
            int b_ = row >> 11, t_ = row & (TT - 1);
            out[((size_t)proj << 23) +
                ((((size_t)b_ * HH + h_) * TT + t_) << 6) + d_] =
                (__bf16)(acc[mq][m4][n2][i] + bb);
          }
        }
      }
  } else {
    // V: transpose 256x128 tile through LDS (2 chunks of 64 cols = 1 head
    // each) and write Vt[bh][d][t] coalesced. LDS main buffers are free.
    __bf16* lt = (__bf16*)&LA[0][0][0];          // [64 cols][264 rows]
    const int cv0 = (bn & 7) << 7;               // col offset within V region
    const int b_ = brow >> 11, t0 = brow & (TT - 1);
    const int hbase = (bn & 7) << 1;
    const int rd_d = tid >> 3, rd_tb = (tid & 7) << 5;
#pragma unroll
    for (int cc = 0; cc < 2; ++cc) {
      if ((wn >> 1) == cc) {                     // 4 writer waves per chunk
#pragma unroll
        for (int n2 = 0; n2 < 2; ++n2) {
          int c = ((wn & 1) << 5) + (n2 << 4) + lq;
          float bb = b2[cv0 + (cc << 6) + c];
#pragma unroll
          for (int mq = 0; mq < 2; ++mq)
#pragma unroll
            for (int m4 = 0; m4 < 4; ++m4) {
              int r = (mq << 7) + (wm << 6) + (m4 << 4) + (g << 2);
              bf16x4 pk;
#pragma unroll
              for (int i = 0; i < 4; ++i)
                pk[i] = (__bf16)(acc[mq][m4][n2][i] + bb);
              *(bf16x4*)(lt + c * 264 + r) = pk;
            }
        }
      }
      __syncthreads();
      // readers: all 512 threads; d = tid>>3, 32 t-elems each
      __bf16* dst = vt + (((size_t)((b_ * HH + hbase + cc) * HD + rd_d)) << 11)
                       + t0 + rd_tb;
      const __bf16* srcl = lt + rd_d * 264 + rd_tb;
#pragma unroll
      for (int j = 0; j < 4; ++j)
        *(bf16x8*)(dst + j * 8) = *(const bf16x8*)(srcl + j * 8);
      __syncthreads();
    }
  }
}

// ---------------- proj GEMM (m97 structure): fp32 out ----------------
__global__ __launch_bounds__(256, 2)
void gemm_proj(const __bf16* __restrict__ A, const __bf16* __restrict__ Bm,
               const float* __restrict__ bias, float* __restrict__ out,
               int M, int N, int K) {
  __shared__ __bf16 As[128 * 32];
  __shared__ __bf16 Bs[128 * 32];
  const int tid = threadIdx.x;
  const int wid = tid >> 6, lane = tid & 63;
  const int g = lane >> 4, lq = lane & 15;
  const int nbn = N >> 7;
  // XCD-chunk swizzle (bijective when gridDim.x % 8 == 0; our launch: 512)
  int bx = blockIdx.x;
  const int nb = gridDim.x;
  if ((nb & 7) == 0) { const int q = nb >> 3; bx = (bx & 7) * q + (bx >> 3); }
  const int brow = (bx / nbn) << 7;
  const int bcol = (bx % nbn) << 7;
  const int wr = (wid >> 1) << 6, wc = (wid & 1) << 6;

  f32x4 acc[4][4] = {};

  const int o0 = wid * 2048 + lane * 16;
  for (int kt = 0; kt < K; kt += 32) {
    __syncthreads();
#pragma unroll
    for (int j = 0; j < 2; ++j) {
      int o = o0 + j * 1024;
      int row = o >> 6, colb = o & 63;
      gload_lds16((const char*)A + ((size_t)(brow + row) * K + kt) * 2 + colb,
                  (char*)As + o);
      gload_lds16((const char*)Bm + ((size_t)(bcol + row) * K + kt) * 2 + colb,
                  (char*)Bs + o);
    }
    __syncthreads();
    bf16x8 av[4], bv[4];
#pragma unroll
    for (int m = 0; m < 4; ++m)
      av[m] = *(const bf16x8*)(As + (wr + m * 16 + lq) * 32 + g * 8);
#pragma unroll
    for (int n = 0; n < 4; ++n)
      bv[n] = *(const bf16x8*)(Bs + (wc + n * 16 + lq) * 32 + g * 8);
#pragma unroll
    for (int m = 0; m < 4; ++m)
#pragma unroll
      for (int n = 0; n < 4; ++n)
        acc[m][n] = __builtin_amdgcn_mfma_f32_16x16x32_bf16(av[m], bv[n], acc[m][n], 0, 0, 0);
  }

#pragma unroll
  for (int m = 0; m < 4; ++m) {
#pragma unroll
    for (int n = 0; n < 4; ++n) {
      int col = bcol + wc + n * 16 + lq;
      float bb = bias[col];
      int row0 = brow + wr + m * 16 + g * 4;
#pragma unroll
      for (int i = 0; i < 4; ++i)
        out[(size_t)(row0 + i) * N + col] = acc[m][n][i] + bb;
    }
  }
}

// ---------------- Flash attention v6 (causal + padding mask) ----------------
// grid 1024 = 16 q-tiles x 64 bh, 256 threads = 4 waves x 32 q-rows (QBLK=128).
// 32x32x16 MFMA, swapped QK^T, split-half S, in-register softmax.
// Full-grid residency: double-buffered K/V (32.8KB LDS) + launch_bounds(256,4)
// -> 4 blocks/CU -> all 1024 blocks co-resident. Heavy-first Latin-square qi
// map balances per-CU work. One barrier per tile, counted staging.
// C/D layout (m74/m101): col = lane&31, row = (r&3) + 8*(r>>2) + 4*(lane>>5).
__global__ __launch_bounds__(256, 4)
void attn_fwd(const __bf16* __restrict__ Q, const __bf16* __restrict__ K,
              const __bf16* __restrict__ Vt, const int* __restrict__ pm,
              __bf16* __restrict__ Y) {
  __shared__ __bf16 Ks[2][64 * 64];   // 16 KiB
  __shared__ __bf16 Vs[2][64 * 64];   // 16 KiB
  __shared__ int flg;
  const int tid = threadIdx.x, wid = tid >> 6, lane = tid & 63;
  const int l31 = lane & 31, hi = lane >> 5;
  const int bx = blockIdx.x;
  const int bh = bx & 63, jj = bx >> 6;          // jj 0..15
  const int qi = 15 - (4 * (jj >> 2) + ((jj + (jj >> 2)) & 3));
  const int b_ = bh >> 4, h_ = bh & 15;
  const __bf16* Qb = Q + (size_t)bh * TT * HD;
  const __bf16* Kb = K + (size_t)bh * TT * HD;
  const __bf16* Vb = Vt + (size_t)bh * HD * TT;
  const int* pmb = pm + b_ * TT;

  const int so = tid * 16;                 // 16B chunk, 0..4080
  const int srow = tid >> 3;               // 0..31
  const int scol = (so & 127) ^ ((srow & 7) << 4);   // inverse-swizzled src col

  const int q0 = qi << 7;
  const int qw = q0 + wid * 32;            // this wave's 32 q-rows
  const int ntiles = 2 * qi + 2;           // >= 2 always
  const int sw0 = (l31 & 7) << 4;

  // Q fragments: lane holds Q[qw+l31][16s + 8hi .. +7], s=0..3
  bf16x8 qf[4];
#pragma unroll
  for (int s = 0; s < 4; ++s)
    qf[s] = *(const bf16x8*)(Qb + (size_t)(qw + l31) * HD + s * 16 + hi * 8);
  SB0;   // pin qf loads above the staging issues (vmcnt accounting)

  // padding-mask block check: 256 threads x 2 int4 cover the 2048-int pm row
  int4 pa4 = ((const int4*)pmb)[tid];
  int4 pb4 = ((const int4*)pmb)[tid + 256];
  bool okp = pa4.x && pa4.y && pa4.z && pa4.w &&
             pb4.x && pb4.y && pb4.z && pb4.w;
  if (tid == 0) flg = 1;
  __syncthreads();
  if (!okp) flg = 0;                       // benign race (all writers store 0)

  // prologue: stage tile 0 into buf 0 (4 gloads: 2 K + 2 V)
  {
    char* kd = (char*)&Ks[0][0] + so;
    char* vd = (char*)&Vs[0][0] + so;
#pragma unroll
    for (int j = 0; j < 2; ++j) {
      gload_lds16((const char*)Kb + (size_t)(srow + 32 * j) * 128 + scol,
                  kd + j * 4096);
      gload_lds16((const char*)Vb + (size_t)(srow + 32 * j) * (TT * 2) + scol,
                  vd + j * 4096);
    }
  }
  __syncthreads();                         // tile 0 staged everywhere; flg final
  const bool allones = (flg != 0);

  f32x16 o0 = {}, o1 = {};                 // O[q=crow(r,hi)][d = l31 | 32+l31]
  f32x16 vzero = {};                       // persistent zero C-operand
  float lsum = 0.f;                        // partial row-sum (this lane-half)
  float m = -INFINITY;                     // running max for q = qw+l31

  int cur = 0;
#pragma unroll 1
  for (int t = 0; t < ntiles; ++t) {
    const int kv0 = t << 6;
    // ---- own stage(t) done (issued a full compute phase ago -> cheap) ----
    WAITV0;
    BARR; SB0;   // all waves: tile t staged AND tile t-1 reads finished
    // ---- issue stage(t+1) into buf[cur^1] (tile t-1's slot, now free) ----
    if (t + 1 < ntiles) {
      char* kd = (char*)&Ks[0][0] + (cur ^ 1) * 8192 + so;
      char* vd = (char*)&Vs[0][0] + (cur ^ 1) * 8192 + so;
      const size_t nk = (size_t)(kv0 + 64);
#pragma unroll
      for (int j = 0; j < 2; ++j) {
        gload_lds16((const char*)Kb + (nk + srow + 32 * j) * 128 + scol,
                    kd + j * 4096);
        gload_lds16((const char*)Vb + (size_t)(srow + 32 * j) * (TT * 2) +
                        nk * 2 + scol,
                    vd + j * 4096);
      }
    }

    unsigned long long bits = ~0ull;
    if (__builtin_expect(!allones, 0))     // rare slow path
      bits = __ballot(pmb[kv0 + lane] != 0);

    if (kv0 <= qw + 31) {                  // wave-uniform participation
      const char* VsC = (const char*)&Vs[0][0] + cur * 8192;

#pragma unroll
      for (int h = 0; h < 2; ++h) {
        const int kvh = kv0 + 32 * h;
        if (kvh <= qw + 31) {              // wave-uniform per-half gate
          // ---- QK^T (swapped): S[kvh+crow][q=l31] ----
          const char* KsC =
              (const char*)&Ks[0][0] + cur * 8192 + (32 * h + l31) * 128;
          f32x16 S;
          __builtin_amdgcn_s_setprio(1);
          {
            bf16x8 k0 = *(const bf16x8*)(KsC + ((16 * hi) ^ sw0));
            S = __builtin_amdgcn_mfma_f32_32x32x16_bf16(k0, qf[0], vzero, 0, 0, 0);
          }
#pragma unroll
          for (int s = 1; s < 4; ++s) {
            bf16x8 kf = *(const bf16x8*)(KsC + ((32 * s + 16 * hi) ^ sw0));
            S = __builtin_amdgcn_mfma_f32_32x32x16_bf16(kf, qf[s], S, 0, 0, 0);
          }
          __builtin_amdgcn_s_setprio(0);

          // ---- masks ----
          if (__builtin_expect(bits != ~0ull, 0)) {   // padding (rare)
#pragma unroll
            for (int r = 0; r < 16; ++r) {
              const int c = (r & 3) + 8 * (r >> 2);
              if (!((bits >> (32 * h + c + 4 * hi)) & 1ull)) S[r] = -INFINITY;
            }
          }
          if (kvh + 31 > qw) {             // causal diag (wave-uniform)
            const int thr = qw + l31 - kvh - 4 * hi;
#pragma unroll
            for (int r = 0; r < 16; ++r) {
              const int c = (r & 3) + 8 * (r >> 2);
              S[r] = (c <= thr) ? S[r] : -INFINITY;
            }
          }

          // ---- row max via packed-f32 tree + defer-rescale check ----
          f32x2 x0 = {S[0], S[1]},  x1 = {S[2], S[3]};
          f32x2 x2 = {S[4], S[5]},  x3 = {S[6], S[7]};
          f32x2 x4 = {S[8], S[9]},  x5 = {S[10], S[11]};
          f32x2 x6 = {S[12], S[13]}, x7 = {S[14], S[15]};
          x0 = max2(x0, x4); x1 = max2(x1, x5);
          x2 = max2(x2, x6); x3 = max2(x3, x7);
          x0 = max2(x0, x2); x1 = max2(x1, x3);
          x0 = max2(x0, x1);
          float pmax = fmaxf(x0[0], x0[1]);
          if (!__all(pmax <= m + 8.f)) {
            float nm = fmaxf(pmax, __shfl_xor(pmax, 32));  // full row max
            float mn = fmaxf(m, nm);
            float c = fast_exp2(m - mn);
            m = mn;
            lsum *= c;
#pragma unroll
            for (int r = 0; r < 16; ++r) {
              float cr = __shfl(c, (r & 3) + 8 * (r >> 2) + 4 * hi);
              o0[r] *= cr;
              o1[r] *= cr;
            }
          }

          // ---- P = exp2(S - m) (packed sub, trans exp) ----
          const f32x2 mm = {m, m};
#pragma unroll
          for (int r = 0; r < 16; r += 2) {
            f32x2 u = {S[r], S[r + 1]};
            u -= mm;                      // v_pk_add_f32
            S[r] = fast_exp2(u[0]);
            S[r + 1] = fast_exp2(u[1]);
          }
          // ---- in-lane row-sum via packed-f32 tree ----
          {
            f32x2 u0 = {S[0], S[1]},  u1 = {S[2], S[3]};
            f32x2 u2 = {S[4], S[5]},  u3 = {S[6], S[7]};
            f32x2 u4 = {S[8], S[9]},  u5 = {S[10], S[11]};
            f32x2 u6 = {S[12], S[13]}, u7 = {S[14], S[15]};
            u0 += u4; u1 += u5; u2 += u6; u3 += u7;
            u0 += u2; u1 += u3;
            u0 += u1;
            lsum += u0[0] + u0[1];
          }

          // ---- PV: build A-fragments (validated select+shfl_xor exchange) ----
          __builtin_amdgcn_s_setprio(1);
#pragma unroll
          for (int s = 0; s < 2; ++s) {
            int A0 = cvt_pk_bf16(S[8 * s + 0], S[8 * s + 1]);
            int A1 = cvt_pk_bf16(S[8 * s + 2], S[8 * s + 3]);
            int B0 = cvt_pk_bf16(S[8 * s + 4], S[8 * s + 5]);
            int B1 = cvt_pk_bf16(S[8 * s + 6], S[8 * s + 7]);
            // exchange across lane+-32: lo lanes need A-pairs of BOTH halves,
            // hi lanes need B-pairs of BOTH halves.
            int s0 = hi ? A0 : B0, s1 = hi ? A1 : B1;
            int e0 = __shfl_xor(s0, 32), e1 = __shfl_xor(s1, 32);
            i32x4 wv;
            wv[0] = hi ? e0 : A0;
            wv[1] = hi ? e1 : A1;
            wv[2] = hi ? B0 : e0;
            wv[3] = hi ? B1 : e1;
            bf16x8 pa = __builtin_bit_cast(bf16x8, wv);
            const int co = 64 * h + 32 * s + 16 * hi;   // kv byte offset
            bf16x8 v0 = *(const bf16x8*)(VsC + l31 * 128 + (co ^ sw0));
            bf16x8 v1 = *(const bf16x8*)(VsC + (32 + l31) * 128 + (co ^ sw0));
            o0 = __builtin_amdgcn_mfma_f32_32x32x16_bf16(pa, v0, o0, 0, 0, 0);
            o1 = __builtin_amdgcn_mfma_f32_32x32x16_bf16(pa, v1, o1, 0, 0, 0);
          }
          __builtin_amdgcn_s_setprio(0);
        }
      }
    }
    SB0;   // pin this tile's LDS reads above next iteration's barrier
    cur ^= 1;
  }

  // epilogue: combine lane-halves' row-sums, normalize + store
  float linv = 1.f / (lsum + __shfl_xor(lsum, 32));
#pragma unroll
  for (int r = 0; r < 16; ++r) {
    const int crow = (r & 3) + 8 * (r >> 2) + 4 * hi;
    float ir = __shfl(linv, crow);
    const int qrow = qw + crow;
    __bf16* yp = Y + ((size_t)(b_ * TT + qrow)) * CC + h_ * HD + l31;
    yp[0]  = (__bf16)(o0[r] * ir);
    yp[32] = (__bf16)(o1[r] * ir);
  }
}

// ---------------- launch ----------------
extern "C" void kernel_launch(void* const* d_in, const int* in_sizes, int n_in,
                              void* d_out, int out_size, void* d_ws, size_t ws_size,
                              hipStream_t stream) {
  (void)in_sizes; (void)n_in; (void)out_size; (void)ws_size;
  const float* x  = (const float*)d_in[0];
  const float* Wk = (const float*)d_in[1];
  const float* bk = (const float*)d_in[2];
  const float* Wq = (const float*)d_in[3];
  const float* bq = (const float*)d_in[4];
  const float* Wv = (const float*)d_in[5];
  const float* bv = (const float*)d_in[6];
  const float* Wp = (const float*)d_in[7];
  const float* bp = (const float*)d_in[8];
  const int* pmask = (const int*)d_in[9];

  char* ws = (char*)d_ws;
  const size_t MB = 1024 * 1024;
  __bf16* xb   = (__bf16*)(ws);            // 16MB; reused as attn-out y
  __bf16* wqkv = (__bf16*)(ws + 16 * MB);  // 6MB  [3072][1024] (q,k,v concat)
  __bf16* wpb  = (__bf16*)(ws + 22 * MB);  // 2MB
  __bf16* qb   = (__bf16*)(ws + 24 * MB);  // 16MB [B,H,T,HD]
  __bf16* kb   = qb + ((size_t)1 << 23);   // 16MB @40MB
  __bf16* vtb  = (__bf16*)(ws + 56 * MB);  // 16MB [B,H,HD,T] (written by gemm_qkv)
  __bf16* yb   = xb;                       // attn out overwrites x

  int n4 = (MM * CC) / 4;                  // 2097152
  cvt_f32_bf16<<<(n4 + 255) / 256, 256, 0, stream>>>(x, xb, n4);
  cvt_w4<<<dim3((CC * CC / 4) / 256, 4), 256, 0, stream>>>(
      Wq, Wk, Wv, Wp, wqkv, wpb);

  // fused QKV projection + V-transpose epilogue (256x128 tiles, grid 768)
  gemm_qkv<<<(MM / 256) * (3 * CC / 128), 512, 0, stream>>>(
      xb, wqkv, bq, bk, bv, qb, vtb);

  attn_fwd<<<NQT2 * BB * HH, 256, 0, stream>>>(qb, kb, vtb, pmask, yb);

  gemm_proj<<<(MM / 128) * (CC / 128), 256, 0, stream>>>(
      yb, wpb, bp, (float*)d_out, MM, CC, CC);
}

// Round 9
// 171.933 us; speedup vs baseline: 1.1384x; 1.0070x over previous
//
#include <hip/hip_runtime.h>
#include <hip/hip_bf16.h>
#include <math.h>
#include <stdint.h>

// Problem constants (reference: B=4, T=2048, C=1024, H=16, HD=64)
#define BB 4
#define TT 2048
#define CC 1024
#define HH 16
#define HD 64
#define MM (BB*TT)   // 8192
#define NQT2 16      // T / 128 q-tiles for attention (QBLK=128)
#define SCQ 0.180336878f   // (1/sqrt(HD)) * log2(e): Q pre-scale for exp2-domain softmax

using f32x2  = __attribute__((ext_vector_type(2))) float;
using f32x4  = __attribute__((ext_vector_type(4))) float;
using f32x16 = __attribute__((ext_vector_type(16))) float;
using i32x4  = __attribute__((ext_vector_type(4))) int;
using bf16x4 = __attribute__((ext_vector_type(4))) __bf16;
using bf16x8 = __attribute__((ext_vector_type(8))) __bf16;

__device__ __forceinline__ float fast_exp2(float x) {
  return __builtin_amdgcn_exp2f(x);   // v_exp_f32 (native exp2 on gfx950)
}

__device__ __forceinline__ int cvt_pk_bf16(float lo, float hi_) {
  int r;
  asm("v_cvt_pk_bf16_f32 %0, %1, %2" : "=v"(r) : "v"(lo), "v"(hi_));
  return r;   // low 16 = bf16(lo), high 16 = bf16(hi_)
}

__device__ __forceinline__ f32x2 max2(f32x2 a, f32x2 b) {
  return __builtin_elementwise_max(a, b);   // v_pk_max_f32
}

__device__ __forceinline__ void gload_lds16(const void* g, void* l) {
  __builtin_amdgcn_global_load_lds(
      (__attribute__((address_space(1))) void*)(void*)(g),
      (__attribute__((address_space(3))) void*)(l), 16, 0, 0);
}

// ---------------- fp32 -> bf16 converts ----------------
__global__ __launch_bounds__(256)
void cvt_f32_bf16(const float* __restrict__ s, __bf16* __restrict__ d, int n4) {
  int i = blockIdx.x * 256 + threadIdx.x;
  if (i >= n4) return;
  float4 v = ((const float4*)s)[i];
  bf16x4 o;
  o[0] = (__bf16)v.x; o[1] = (__bf16)v.y; o[2] = (__bf16)v.z; o[3] = (__bf16)v.w;
  *(bf16x4*)(d + (size_t)i * 4) = o;
}

// 4 weights in one launch; Wq scaled by SCQ and Wq/Wk/Wv written into the
// contiguous [3072][1024] concat buffer (order q,k,v); Wp separate.
__global__ __launch_bounds__(256)
void cvt_w4(const float* __restrict__ Wq, const float* __restrict__ Wk,
            const float* __restrict__ Wv, const float* __restrict__ Wp,
            __bf16* __restrict__ wqkv, __bf16* __restrict__ wpb) {
  int which = blockIdx.y;
  const float* s = which == 0 ? Wq : which == 1 ? Wk : which == 2 ? Wv : Wp;
  __bf16* d = which == 3 ? wpb : wqkv + (size_t)which * CC * CC;
  float sc = which == 0 ? SCQ : 1.f;
  int i = blockIdx.x * 256 + threadIdx.x;   // grid.x = (CC*CC/4)/256 = 1024
  float4 v = ((const float4*)s)[i];
  bf16x4 o;
  o[0] = (__bf16)(v.x * sc); o[1] = (__bf16)(v.y * sc);
  o[2] = (__bf16)(v.z * sc); o[3] = (__bf16)(v.w * sc);
  *(bf16x4*)(d + (size_t)i * 4) = o;
}

#define WAITV0 asm volatile("s_waitcnt vmcnt(0)" ::: "memory")
#define SB0    __builtin_amdgcn_sched_barrier(0)

// ============ QKV GEMM v9: m97 128x128 BK=32 structure (gemm_proj clone) ====
// C[8192,3072] = A[8192,1024] x Wqkv[3072,1024]^T + bias.
// Rationale (r8 post-mortem): the 8-phase 1-block/CU lockstep was
// per-phase-latency-bound (~1450-1940 cy/phase vs 620 cy MFMA content) and
// invariant to tile shape / fetch locality / grid quantization. The m97
// structure (proven 912 TF; our gemm_proj is this skeleton, validated every
// round) uses 33KB LDS + 256 thr -> 4 blocks/CU: cross-block overlap fills
// the staging gaps automatically. Grid 64x24 = 1536 = 6.0 blocks/CU exact.
// proj 0/1 (Q,K): bf16 head-split store [proj][B,H,T,HD].
// proj 2 (V): 128x128 tile transposed through lt[64][130] in 2 chunks of
// 64 cols (2 heads/tile) -> Vt[bh][d][t] coalesced.
__global__ __launch_bounds__(256, 2)
void gemm_qkv(const __bf16* __restrict__ A, const __bf16* __restrict__ Bm,
              const float* __restrict__ b0, const float* __restrict__ b1,
              const float* __restrict__ b2, __bf16* __restrict__ out,
              __bf16* __restrict__ vt) {
  __shared__ __bf16 As[128 * 32];    // 8 KB
  __shared__ __bf16 Bs[128 * 32];    // 8 KB
  __shared__ __bf16 lt[64 * 130];    // 16.6 KB V-transpose buffer
  const int tid = threadIdx.x;
  const int wid = tid >> 6, lane = tid & 63;
  const int g = lane >> 4, lq = lane & 15;
  // XCD-chunk swizzle: 1536 blocks = 8 XCDs x 192 contiguous logicals
  const int bx0 = blockIdx.x;
  const int bx = (bx0 & 7) * 192 + (bx0 >> 3);
  const int bm = bx / 24, bn = bx % 24;
  const int brow = bm << 7, bcol = bn << 7;
  const int wr = (wid >> 1) << 6, wc = (wid & 1) << 6;

  f32x4 acc[4][4] = {};

  const int o0 = wid * 2048 + lane * 16;
  for (int kt = 0; kt < CC; kt += 32) {
    __syncthreads();
#pragma unroll
    for (int j = 0; j < 2; ++j) {
      int o = o0 + j * 1024;
      int row = o >> 6, colb = o & 63;
      gload_lds16((const char*)A + ((size_t)(brow + row) * CC + kt) * 2 + colb,
                  (char*)As + o);
      gload_lds16((const char*)Bm + ((size_t)(bcol + row) * CC + kt) * 2 + colb,
                  (char*)Bs + o);
    }
    __syncthreads();
    bf16x8 av[4], bv[4];
#pragma unroll
    for (int m = 0; m < 4; ++m)
      av[m] = *(const bf16x8*)(As + (wr + m * 16 + lq) * 32 + g * 8);
#pragma unroll
    for (int n = 0; n < 4; ++n)
      bv[n] = *(const bf16x8*)(Bs + (wc + n * 16 + lq) * 32 + g * 8);
#pragma unroll
    for (int m = 0; m < 4; ++m)
#pragma unroll
      for (int n = 0; n < 4; ++n)
        acc[m][n] = __builtin_amdgcn_mfma_f32_16x16x32_bf16(av[m], bv[n], acc[m][n], 0, 0, 0);
  }

  const int proj = bn >> 3;   // uniform per block (8 x 128 = 1024 cols / proj)
  if (proj < 2) {
    // epilogue: bias + bf16 head-split store [proj][B,H,T,HD]
    const float* bias = proj == 0 ? b0 : b1;
    const float bsc = proj == 0 ? SCQ : 1.f;
#pragma unroll
    for (int n = 0; n < 4; ++n) {
      int col = bcol + wc + n * 16 + lq;
      int cw = col & (CC - 1);
      float bb = bias[cw] * bsc;
      int h_ = cw >> 6, d_ = cw & (HD - 1);
#pragma unroll
      for (int m = 0; m < 4; ++m) {
        int row0 = brow + wr + m * 16 + g * 4;
#pragma unroll
        for (int i = 0; i < 4; ++i) {
          int row = row0 + i;
          int b_ = row >> 11, t_ = row & (TT - 1);
          out[((size_t)proj << 23) +
              ((((size_t)b_ * HH + h_) * TT + t_) << 6) + d_] =
              (__bf16)(acc[m][n][i] + bb);
        }
      }
    }
  } else {
    // V: transpose 128x128 tile through lt (2 chunks of 64 cols = 1 head
    // each) and write Vt[bh][d][t] coalesced.
    const int cv0 = (bn & 7) << 7;               // col offset within V region
    const int b_ = brow >> 11, t0 = brow & (TT - 1);
    const int hbase = (bn & 7) << 1;
    const int rd_d = tid >> 2, rd_tb = (tid & 3) << 5;   // 64 d x 128 t
#pragma unroll
    for (int cc = 0; cc < 2; ++cc) {
      if ((wid & 1) == cc) {                     // 2 writer waves per chunk
#pragma unroll
        for (int n = 0; n < 4; ++n) {
          int c = (n << 4) + lq;                 // 0..63 within chunk
          float bb = b2[cv0 + (cc << 6) + c];
#pragma unroll
          for (int m = 0; m < 4; ++m) {
            int r = wr + (m << 4) + (g << 2);    // 0..127 over both writers
            bf16x4 pk;
#pragma unroll
            for (int i = 0; i < 4; ++i)
              pk[i] = (__bf16)(acc[m][n][i] + bb);
            *(bf16x4*)(lt + c * 130 + r) = pk;
          }
        }
      }
      __syncthreads();
      // readers: all 256 threads; d = tid>>2, 32 t-elems each
      __bf16* dst = vt + (((size_t)((b_ * HH + hbase + cc) * HD + rd_d)) << 11)
                       + t0 + rd_tb;
      const __bf16* srcl = lt + rd_d * 130 + rd_tb;
#pragma unroll
      for (int j = 0; j < 4; ++j)
        *(bf16x8*)(dst + j * 8) = *(const bf16x8*)(srcl + j * 8);
      __syncthreads();
    }
  }
}

// ---------------- proj GEMM (m97 structure): fp32 out ----------------
__global__ __launch_bounds__(256, 2)
void gemm_proj(const __bf16* __restrict__ A, const __bf16* __restrict__ Bm,
               const float* __restrict__ bias, float* __restrict__ out,
               int M, int N, int K) {
  __shared__ __bf16 As[128 * 32];
  __shared__ __bf16 Bs[128 * 32];
  const int tid = threadIdx.x;
  const int wid = tid >> 6, lane = tid & 63;
  const int g = lane >> 4, lq = lane & 15;
  const int nbn = N >> 7;
  // XCD-chunk swizzle (bijective when gridDim.x % 8 == 0; our launch: 512)
  int bx = blockIdx.x;
  const int nb = gridDim.x;
  if ((nb & 7) == 0) { const int q = nb >> 3; bx = (bx & 7) * q + (bx >> 3); }
  const int brow = (bx / nbn) << 7;
  const int bcol = (bx % nbn) << 7;
  const int wr = (wid >> 1) << 6, wc = (wid & 1) << 6;

  f32x4 acc[4][4] = {};

  const int o0 = wid * 2048 + lane * 16;
  for (int kt = 0; kt < K; kt += 32) {
    __syncthreads();
#pragma unroll
    for (int j = 0; j < 2; ++j) {
      int o = o0 + j * 1024;
      int row = o >> 6, colb = o & 63;
      gload_lds16((const char*)A + ((size_t)(brow + row) * K + kt) * 2 + colb,
                  (char*)As + o);
      gload_lds16((const char*)Bm + ((size_t)(bcol + row) * K + kt) * 2 + colb,
                  (char*)Bs + o);
    }
    __syncthreads();
    bf16x8 av[4], bv[4];
#pragma unroll
    for (int m = 0; m < 4; ++m)
      av[m] = *(const bf16x8*)(As + (wr + m * 16 + lq) * 32 + g * 8);
#pragma unroll
    for (int n = 0; n < 4; ++n)
      bv[n] = *(const bf16x8*)(Bs + (wc + n * 16 + lq) * 32 + g * 8);
#pragma unroll
    for (int m = 0; m < 4; ++m)
#pragma unroll
      for (int n = 0; n < 4; ++n)
        acc[m][n] = __builtin_amdgcn_mfma_f32_16x16x32_bf16(av[m], bv[n], acc[m][n], 0, 0, 0);
  }

#pragma unroll
  for (int m = 0; m < 4; ++m) {
#pragma unroll
    for (int n = 0; n < 4; ++n) {
      int col = bcol + wc + n * 16 + lq;
      float bb = bias[col];
      int row0 = brow + wr + m * 16 + g * 4;
#pragma unroll
      for (int i = 0; i < 4; ++i)
        out[(size_t)(row0 + i) * N + col] = acc[m][n][i] + bb;
    }
  }
}

// ---------------- Flash attention v6 (causal + padding mask) ----------------
// grid 1024 = 16 q-tiles x 64 bh, 256 threads = 4 waves x 32 q-rows (QBLK=128).
// 32x32x16 MFMA, swapped QK^T, split-half S, in-register softmax.
// Full-grid residency: double-buffered K/V (32.8KB LDS) + launch_bounds(256,4)
// -> 4 blocks/CU -> all 1024 blocks co-resident. Heavy-first Latin-square qi
// map balances per-CU work. One barrier per tile, counted staging.
// C/D layout (m74/m101): col = lane&31, row = (r&3) + 8*(r>>2) + 4*(lane>>5).
__global__ __launch_bounds__(256, 4)
void attn_fwd(const __bf16* __restrict__ Q, const __bf16* __restrict__ K,
              const __bf16* __restrict__ Vt, const int* __restrict__ pm,
              __bf16* __restrict__ Y) {
  __shared__ __bf16 Ks[2][64 * 64];   // 16 KiB
  __shared__ __bf16 Vs[2][64 * 64];   // 16 KiB
  __shared__ int flg;
  const int tid = threadIdx.x, wid = tid >> 6, lane = tid & 63;
  const int l31 = lane & 31, hi = lane >> 5;
  const int bx = blockIdx.x;
  const int bh = bx & 63, jj = bx >> 6;          // jj 0..15
  const int qi = 15 - (4 * (jj >> 2) + ((jj + (jj >> 2)) & 3));
  const int b_ = bh >> 4, h_ = bh & 15;
  const __bf16* Qb = Q + (size_t)bh * TT * HD;
  const __bf16* Kb = K + (size_t)bh * TT * HD;
  const __bf16* Vb = Vt + (size_t)bh * HD * TT;
  const int* pmb = pm + b_ * TT;

  const int so = tid * 16;                 // 16B chunk, 0..4080
  const int srow = tid >> 3;               // 0..31
  const int scol = (so & 127) ^ ((srow & 7) << 4);   // inverse-swizzled src col

  const int q0 = qi << 7;
  const int qw = q0 + wid * 32;            // this wave's 32 q-rows
  const int ntiles = 2 * qi + 2;           // >= 2 always
  const int sw0 = (l31 & 7) << 4;

  // Q fragments: lane holds Q[qw+l31][16s + 8hi .. +7], s=0..3
  bf16x8 qf[4];
#pragma unroll
  for (int s = 0; s < 4; ++s)
    qf[s] = *(const bf16x8*)(Qb + (size_t)(qw + l31) * HD + s * 16 + hi * 8);
  SB0;   // pin qf loads above the staging issues (vmcnt accounting)

  // padding-mask block check: 256 threads x 2 int4 cover the 2048-int pm row
  int4 pa4 = ((const int4*)pmb)[tid];
  int4 pb4 = ((const int4*)pmb)[tid + 256];
  bool okp = pa4.x && pa4.y && pa4.z && pa4.w &&
             pb4.x && pb4.y && pb4.z && pb4.w;
  if (tid == 0) flg = 1;
  __syncthreads();
  if (!okp) flg = 0;                       // benign race (all writers store 0)

  // prologue: stage tile 0 into buf 0 (4 gloads: 2 K + 2 V)
  {
    char* kd = (char*)&Ks[0][0] + so;
    char* vd = (char*)&Vs[0][0] + so;
#pragma unroll
    for (int j = 0; j < 2; ++j) {
      gload_lds16((const char*)Kb + (size_t)(srow + 32 * j) * 128 + scol,
                  kd + j * 4096);
      gload_lds16((const char*)Vb + (size_t)(srow + 32 * j) * (TT * 2) + scol,
                  vd + j * 4096);
    }
  }
  __syncthreads();                         // tile 0 staged everywhere; flg final
  const bool allones = (flg != 0);

  f32x16 o0 = {}, o1 = {};                 // O[q=crow(r,hi)][d = l31 | 32+l31]
  f32x16 vzero = {};                       // persistent zero C-operand
  float lsum = 0.f;                        // partial row-sum (this lane-half)
  float m = -INFINITY;                     // running max for q = qw+l31

  int cur = 0;
#pragma unroll 1
  for (int t = 0; t < ntiles; ++t) {
    const int kv0 = t << 6;
    // ---- own stage(t) done (issued a full compute phase ago -> cheap) ----
    WAITV0;
    __builtin_amdgcn_s_barrier(); SB0;  // tile t staged AND t-1 reads done
    // ---- issue stage(t+1) into buf[cur^1] (tile t-1's slot, now free) ----
    if (t + 1 < ntiles) {
      char* kd = (char*)&Ks[0][0] + (cur ^ 1) * 8192 + so;
      char* vd = (char*)&Vs[0][0] + (cur ^ 1) * 8192 + so;
      const size_t nk = (size_t)(kv0 + 64);
#pragma unroll
      for (int j = 0; j < 2; ++j) {
        gload_lds16((const char*)Kb + (nk + srow + 32 * j) * 128 + scol,
                    kd + j * 4096);
        gload_lds16((const char*)Vb + (size_t)(srow + 32 * j) * (TT * 2) +
                        nk * 2 + scol,
                    vd + j * 4096);
      }
    }

    unsigned long long bits = ~0ull;
    if (__builtin_expect(!allones, 0))     // rare slow path
      bits = __ballot(pmb[kv0 + lane] != 0);

    if (kv0 <= qw + 31) {                  // wave-uniform participation
      const char* VsC = (const char*)&Vs[0][0] + cur * 8192;

#pragma unroll
      for (int h = 0; h < 2; ++h) {
        const int kvh = kv0 + 32 * h;
        if (kvh <= qw + 31) {              // wave-uniform per-half gate
          // ---- QK^T (swapped): S[kvh+crow][q=l31] ----
          const char* KsC =
              (const char*)&Ks[0][0] + cur * 8192 + (32 * h + l31) * 128;
          f32x16 S;
          __builtin_amdgcn_s_setprio(1);
          {
            bf16x8 k0 = *(const bf16x8*)(KsC + ((16 * hi) ^ sw0));
            S = __builtin_amdgcn_mfma_f32_32x32x16_bf16(k0, qf[0], vzero, 0, 0, 0);
          }
#pragma unroll
          for (int s = 1; s < 4; ++s) {
            bf16x8 kf = *(const bf16x8*)(KsC + ((32 * s + 16 * hi) ^ sw0));
            S = __builtin_amdgcn_mfma_f32_32x32x16_bf16(kf, qf[s], S, 0, 0, 0);
          }
          __builtin_amdgcn_s_setprio(0);

          // ---- masks ----
          if (__builtin_expect(bits != ~0ull, 0)) {   // padding (rare)
#pragma unroll
            for (int r = 0; r < 16; ++r) {
              const int c = (r & 3) + 8 * (r >> 2);
              if (!((bits >> (32 * h + c + 4 * hi)) & 1ull)) S[r] = -INFINITY;
            }
          }
          if (kvh + 31 > qw) {             // causal diag (wave-uniform)
            const int thr = qw + l31 - kvh - 4 * hi;
#pragma unroll
            for (int r = 0; r < 16; ++r) {
              const int c = (r & 3) + 8 * (r >> 2);
              S[r] = (c <= thr) ? S[r] : -INFINITY;
            }
          }

          // ---- row max via packed-f32 tree + defer-rescale check ----
          f32x2 x0 = {S[0], S[1]},  x1 = {S[2], S[3]};
          f32x2 x2 = {S[4], S[5]},  x3 = {S[6], S[7]};
          f32x2 x4 = {S[8], S[9]},  x5 = {S[10], S[11]};
          f32x2 x6 = {S[12], S[13]}, x7 = {S[14], S[15]};
          x0 = max2(x0, x4); x1 = max2(x1, x5);
          x2 = max2(x2, x6); x3 = max2(x3, x7);
          x0 = max2(x0, x2); x1 = max2(x1, x3);
          x0 = max2(x0, x1);
          float pmax = fmaxf(x0[0], x0[1]);
          if (!__all(pmax <= m + 8.f)) {
            float nm = fmaxf(pmax, __shfl_xor(pmax, 32));  // full row max
            float mn = fmaxf(m, nm);
            float c = fast_exp2(m - mn);
            m = mn;
            lsum *= c;
#pragma unroll
            for (int r = 0; r < 16; ++r) {
              float cr = __shfl(c, (r & 3) + 8 * (r >> 2) + 4 * hi);
              o0[r] *= cr;
              o1[r] *= cr;
            }
          }

          // ---- P = exp2(S - m) (packed sub, trans exp) ----
          const f32x2 mm = {m, m};
#pragma unroll
          for (int r = 0; r < 16; r += 2) {
            f32x2 u = {S[r], S[r + 1]};
            u -= mm;                      // v_pk_add_f32
            S[r] = fast_exp2(u[0]);
            S[r + 1] = fast_exp2(u[1]);
          }
          // ---- in-lane row-sum via packed-f32 tree ----
          {
            f32x2 u0 = {S[0], S[1]},  u1 = {S[2], S[3]};
            f32x2 u2 = {S[4], S[5]},  u3 = {S[6], S[7]};
            f32x2 u4 = {S[8], S[9]},  u5 = {S[10], S[11]};
            f32x2 u6 = {S[12], S[13]}, u7 = {S[14], S[15]};
            u0 += u4; u1 += u5; u2 += u6; u3 += u7;
            u0 += u2; u1 += u3;
            u0 += u1;
            lsum += u0[0] + u0[1];
          }

          // ---- PV: build A-fragments (validated select+shfl_xor exchange) ----
          __builtin_amdgcn_s_setprio(1);
#pragma unroll
          for (int s = 0; s < 2; ++s) {
            int A0 = cvt_pk_bf16(S[8 * s + 0], S[8 * s + 1]);
            int A1 = cvt_pk_bf16(S[8 * s + 2], S[8 * s + 3]);
            int B0 = cvt_pk_bf16(S[8 * s + 4], S[8 * s + 5]);
            int B1 = cvt_pk_bf16(S[8 * s + 6], S[8 * s + 7]);
            // exchange across lane+-32: lo lanes need A-pairs of BOTH halves,
            // hi lanes need B-pairs of BOTH halves.
            int s0 = hi ? A0 : B0, s1 = hi ? A1 : B1;
            int e0 = __shfl_xor(s0, 32), e1 = __shfl_xor(s1, 32);
            i32x4 wv;
            wv[0] = hi ? e0 : A0;
            wv[1] = hi ? e1 : A1;
            wv[2] = hi ? B0 : e0;
            wv[3] = hi ? B1 : e1;
            bf16x8 pa = __builtin_bit_cast(bf16x8, wv);
            const int co = 64 * h + 32 * s + 16 * hi;   // kv byte offset
            bf16x8 v0 = *(const bf16x8*)(VsC + l31 * 128 + (co ^ sw0));
            bf16x8 v1 = *(const bf16x8*)(VsC + (32 + l31) * 128 + (co ^ sw0));
            o0 = __builtin_amdgcn_mfma_f32_32x32x16_bf16(pa, v0, o0, 0, 0, 0);
            o1 = __builtin_amdgcn_mfma_f32_32x32x16_bf16(pa, v1, o1, 0, 0, 0);
          }
          __builtin_amdgcn_s_setprio(0);
        }
      }
    }
    SB0;   // pin this tile's LDS reads above next iteration's barrier
    cur ^= 1;
  }

  // epilogue: combine lane-halves' row-sums, normalize + store
  float linv = 1.f / (lsum + __shfl_xor(lsum, 32));
#pragma unroll
  for (int r = 0; r < 16; ++r) {
    const int crow = (r & 3) + 8 * (r >> 2) + 4 * hi;
    float ir = __shfl(linv, crow);
    const int qrow = qw + crow;
    __bf16* yp = Y + ((size_t)(b_ * TT + qrow)) * CC + h_ * HD + l31;
    yp[0]  = (__bf16)(o0[r] * ir);
    yp[32] = (__bf16)(o1[r] * ir);
  }
}

// ---------------- launch ----------------
extern "C" void kernel_launch(void* const* d_in, const int* in_sizes, int n_in,
                              void* d_out, int out_size, void* d_ws, size_t ws_size,
                              hipStream_t stream) {
  (void)in_sizes; (void)n_in; (void)out_size; (void)ws_size;
  const float* x  = (const float*)d_in[0];
  const float* Wk = (const float*)d_in[1];
  const float* bk = (const float*)d_in[2];
  const float* Wq = (const float*)d_in[3];
  const float* bq = (const float*)d_in[4];
  const float* Wv = (const float*)d_in[5];
  const float* bv = (const float*)d_in[6];
  const float* Wp = (const float*)d_in[7];
  const float* bp = (const float*)d_in[8];
  const int* pmask = (const int*)d_in[9];

  char* ws = (char*)d_ws;
  const size_t MB = 1024 * 1024;
  __bf16* xb   = (__bf16*)(ws);            // 16MB; reused as attn-out y
  __bf16* wqkv = (__bf16*)(ws + 16 * MB);  // 6MB  [3072][1024] (q,k,v concat)
  __bf16* wpb  = (__bf16*)(ws + 22 * MB);  // 2MB
  __bf16* qb   = (__bf16*)(ws + 24 * MB);  // 16MB [B,H,T,HD]
  __bf16* kb   = qb + ((size_t)1 << 23);   // 16MB @40MB
  __bf16* vtb  = (__bf16*)(ws + 56 * MB);  // 16MB [B,H,HD,T] (written by gemm_qkv)
  __bf16* yb   = xb;                       // attn out overwrites x

  int n4 = (MM * CC) / 4;                  // 2097152
  cvt_f32_bf16<<<(n4 + 255) / 256, 256, 0, stream>>>(x, xb, n4);
  cvt_w4<<<dim3((CC * CC / 4) / 256, 4), 256, 0, stream>>>(
      Wq, Wk, Wv, Wp, wqkv, wpb);

  // fused QKV projection + V-transpose epilogue (128x128 tiles, grid 1536)
  gemm_qkv<<<(MM / 128) * (3 * CC / 128), 256, 0, stream>>>(
      xb, wqkv, bq, bk, bv, qb, vtb);

  attn_fwd<<<NQT2 * BB * HH, 256, 0, stream>>>(qb, kb, vtb, pmask, yb);

  gemm_proj<<<(MM / 128) * (CC / 128), 256, 0, stream>>>(
      yb, wpb, bp, (float*)d_out, MM, CC, CC);
}